// Round 1
// baseline (4675.892 us; speedup 1.0000x reference)
//
#include <hip/hip_runtime.h>
#include <hip/hip_bf16.h>
#include <cstdint>

// Problem constants
#define BB 512      // batch
#define TT 128      // time steps
#define VV 50000
#define DD 300      // embed dim
#define HH 512      // hidden
#define MLPD 1024
#define CC 3

typedef __bf16 bf16x8 __attribute__((ext_vector_type(8)));
typedef float  f32x4  __attribute__((ext_vector_type(4)));

struct alignas(8) bf4 { __bf16 x, y, z, w; };

// ---------------------------------------------------------------------------
// Two-level grid barrier (16 sub-counters on distinct 128B lines + master + gen)
// bar layout (unsigned words, 128B-strided): sub[s] at bar+32*s (s=0..15),
// master at bar+32*16, gen at bar+32*17.
// ---------------------------------------------------------------------------
#define NSUB 16
__device__ __forceinline__ void grid_barrier(unsigned* bar) {
    __syncthreads();
    if (threadIdx.x == 0) {
        __threadfence();  // release: agent-scope, flushes L2 for cross-XCD visibility
        unsigned* gen = bar + 32 * 17;
        unsigned g = __hip_atomic_load(gen, __ATOMIC_RELAXED, __HIP_MEMORY_SCOPE_AGENT);
        unsigned* sub = bar + 32 * (blockIdx.x & (NSUB - 1));
        unsigned o = __hip_atomic_fetch_add(sub, 1u, __ATOMIC_ACQ_REL, __HIP_MEMORY_SCOPE_AGENT);
        bool done = false;
        if (o == 16u - 1u) {                       // 256 WGs / 16 subs = 16 per sub
            __hip_atomic_store(sub, 0u, __ATOMIC_RELAXED, __HIP_MEMORY_SCOPE_AGENT);
            unsigned* master = bar + 32 * 16;
            unsigned mo = __hip_atomic_fetch_add(master, 1u, __ATOMIC_ACQ_REL, __HIP_MEMORY_SCOPE_AGENT);
            if (mo == NSUB - 1u) {
                __hip_atomic_store(master, 0u, __ATOMIC_RELAXED, __HIP_MEMORY_SCOPE_AGENT);
                __hip_atomic_store(gen, g + 1u, __ATOMIC_RELEASE, __HIP_MEMORY_SCOPE_AGENT);
                done = true;
            }
        }
        if (!done) {
            long spins = 0;
            while (__hip_atomic_load(gen, __ATOMIC_ACQUIRE, __HIP_MEMORY_SCOPE_AGENT) == g) {
                __builtin_amdgcn_s_sleep(1);
                if (++spins > 20000000L) break;    // safety: never hang the bench
            }
        }
        __threadfence();  // acquire: invalidate L1/L2 so staged h reads are fresh
    }
    __syncthreads();
}

// ---------------------------------------------------------------------------
// Kernel 1: P[t,i,:] = E[x[i,T-1-t]] @ W_ih^T + b_ih + b_hh   (bf16 out)
// 64x64 tiles, K=300 padded to 320, MFMA 16x16x32 bf16.
// Grid: (n_tiles=8, i_tiles=8, t=128), 256 threads.
// Tiles where no row is active at step t are skipped (P never read there).
// ---------------------------------------------------------------------------
#define LKP 328   // LDS k-stride (320 + 8 pad), bf16 elems

__global__ __launch_bounds__(256) void k_proj(
    const int* __restrict__ x, const int* __restrict__ lengths,
    const float* __restrict__ E, const float* __restrict__ W_ih,
    const float* __restrict__ b_ih, const float* __restrict__ b_hh,
    __bf16* __restrict__ P)
{
    __shared__ __bf16 As[64 * LKP];
    __shared__ __bf16 Bs[64 * LKP];
    __shared__ int lens_s[64];
    __shared__ int skip_s;

    const int t   = blockIdx.z;
    const int i0  = blockIdx.y * 64;
    const int n0  = blockIdx.x * 64;
    const int tid = threadIdx.x;

    if (tid < 64) lens_s[tid] = lengths[i0 + tid];
    __syncthreads();
    if (tid == 0) {
        int mx = 0;
        for (int j = 0; j < 64; ++j) mx = mx > lens_s[j] ? mx : lens_s[j];
        skip_s = (mx <= TT - 1 - t) ? 1 : 0;
    }
    __syncthreads();
    if (skip_s) return;

    {   // stage A (gathered embeddings) and B (W_ih) as bf16, zero-pad K to 320
        const int row = tid >> 2, kq = tid & 3;
        const int tok = x[(i0 + row) * TT + (TT - 1 - t)];
        const float* arow = E + (size_t)tok * DD;
        const float* brow = W_ih + (n0 + row) * DD;
        __bf16* adst = &As[row * LKP];
        __bf16* bdst = &Bs[row * LKP];
        #pragma unroll
        for (int f = 0; f < 20; ++f) {
            const int k = kq * 80 + f * 4;
            float4 av = make_float4(0.f, 0.f, 0.f, 0.f);
            float4 bv = make_float4(0.f, 0.f, 0.f, 0.f);
            if (k < DD) { av = *(const float4*)(arow + k); bv = *(const float4*)(brow + k); }
            bf4 ap = {(__bf16)av.x, (__bf16)av.y, (__bf16)av.z, (__bf16)av.w};
            bf4 bp = {(__bf16)bv.x, (__bf16)bv.y, (__bf16)bv.z, (__bf16)bv.w};
            *(bf4*)(adst + k) = ap;
            *(bf4*)(bdst + k) = bp;
        }
    }
    __syncthreads();

    const int wave = tid >> 6, lane = tid & 63;
    const int wm = (wave & 1) * 32, wn = (wave >> 1) * 32;
    const int lr = lane & 15, kk = (lane >> 4) * 8;
    f32x4 acc[2][2] = {};
    #pragma unroll
    for (int kc = 0; kc < 10; ++kc) {
        const int kb = kc * 32 + kk;
        bf16x8 a0 = *(const bf16x8*)(&As[(wm      + lr) * LKP + kb]);
        bf16x8 a1 = *(const bf16x8*)(&As[(wm + 16 + lr) * LKP + kb]);
        bf16x8 b0 = *(const bf16x8*)(&Bs[(wn      + lr) * LKP + kb]);
        bf16x8 b1 = *(const bf16x8*)(&Bs[(wn + 16 + lr) * LKP + kb]);
        acc[0][0] = __builtin_amdgcn_mfma_f32_16x16x32_bf16(a0, b0, acc[0][0], 0, 0, 0);
        acc[0][1] = __builtin_amdgcn_mfma_f32_16x16x32_bf16(a0, b1, acc[0][1], 0, 0, 0);
        acc[1][0] = __builtin_amdgcn_mfma_f32_16x16x32_bf16(a1, b0, acc[1][0], 0, 0, 0);
        acc[1][1] = __builtin_amdgcn_mfma_f32_16x16x32_bf16(a1, b1, acc[1][1], 0, 0, 0);
    }

    // C/D layout (verified m89/m91): col = lane&15 (N), row = (lane>>4)*4 + reg (M)
    const int mrow = (lane >> 4) * 4, ncol = lane & 15;
    #pragma unroll
    for (int ni = 0; ni < 2; ++ni) {
        const int nl = wn + ni * 16 + ncol;
        const float bias = b_ih[n0 + nl] + b_hh[n0 + nl];
        #pragma unroll
        for (int mi = 0; mi < 2; ++mi) {
            #pragma unroll
            for (int r = 0; r < 4; ++r) {
                const int ml = wm + mi * 16 + mrow + r;
                P[(t * BB + (i0 + ml)) * HH + (n0 + nl)] = (__bf16)(acc[mi][ni][r] + bias);
            }
        }
    }
}

// ---------------------------------------------------------------------------
// Kernel 2: persistent recurrence. 256 WGs (16 row-tiles x 16 col-tiles of
// 32x32), W_hh col-slice LDS-resident, h double-buffered bf16 in ws,
// grid barrier per step.
// ---------------------------------------------------------------------------
#define LKH 520   // LDS k-stride for 512-wide tiles (+8 pad)

__global__ __launch_bounds__(256) void k_rnn(
    const int* __restrict__ lengths, const float* __restrict__ W_hh,
    const __bf16* __restrict__ P,
    __bf16* __restrict__ h0, __bf16* __restrict__ h1,
    unsigned* __restrict__ bar)
{
    __shared__ __bf16 Ws_s[32 * LKH];
    __shared__ __bf16 Hs[32 * LKH];
    __shared__ int lens_s[32];

    const int tid = threadIdx.x;
    const int wg  = blockIdx.x;
    const int r0  = (wg >> 4) * 32;   // sample-row tile
    const int c0  = (wg & 15) * 32;   // hidden-col tile

    {   // preload W_hh[c0..c0+32) x [0..512) as bf16 (resident for all steps)
        const int row = tid >> 3, part = tid & 7;
        const float* src = W_hh + (c0 + row) * HH + part * 64;
        __bf16* dst = &Ws_s[row * LKH + part * 64];
        #pragma unroll
        for (int j = 0; j < 64; j += 4) {
            float4 v = *(const float4*)(src + j);
            bf4 pk = {(__bf16)v.x, (__bf16)v.y, (__bf16)v.z, (__bf16)v.w};
            *(bf4*)(dst + j) = pk;
        }
    }
    if (tid < 32) lens_s[tid] = lengths[r0 + tid];
    __syncthreads();

    const int wave = tid >> 6, lane = tid & 63;
    const int wm = (wave & 1) * 16, wn = (wave >> 1) * 16;
    const int lr = lane & 15, kk = (lane >> 4) * 8;
    const int mrow = (lane >> 4) * 4, ncol = lane & 15;

    for (int t = 0; t < TT; ++t) {
        const __bf16* hin  = (t & 1) ? h1 : h0;
        __bf16*       hout = (t & 1) ? h0 : h1;

        {   // stage h_prev rows r0..r0+31 (full K) into LDS
            const int row = tid >> 3, part = tid & 7;
            const __bf16* src = hin + (r0 + row) * HH + part * 64;
            __bf16* dst = &Hs[row * LKH + part * 64];
            #pragma unroll
            for (int j = 0; j < 64; j += 8)
                *(uint4*)(dst + j) = *(const uint4*)(src + j);
        }
        __syncthreads();

        f32x4 acc = {0.f, 0.f, 0.f, 0.f};
        #pragma unroll
        for (int kc = 0; kc < 16; ++kc) {
            const int kb = kc * 32 + kk;
            bf16x8 af = *(const bf16x8*)(&Hs  [(wm + lr) * LKH + kb]);
            bf16x8 bf = *(const bf16x8*)(&Ws_s[(wn + lr) * LKH + kb]);
            acc = __builtin_amdgcn_mfma_f32_16x16x32_bf16(af, bf, acc, 0, 0, 0);
        }

        const int thr_idx = TT - 1 - t;       // token index consumed at step t
        const int gc = c0 + wn + ncol;
        #pragma unroll
        for (int r = 0; r < 4; ++r) {
            const int ml = wm + mrow + r;
            const int gr = r0 + ml;
            float hv;
            if (thr_idx < lens_s[ml]) {
                float pre = acc[r] + (float)P[(t * BB + gr) * HH + gc];
                hv = tanhf(pre);
            } else {
                hv = (float)Hs[ml * LKH + gc];  // carry previous hidden state
            }
            hout[gr * HH + gc] = (__bf16)hv;
        }
        grid_barrier(bar);
    }
    // final h lands in h0 (128 steps, last write -> buffer 0)
}

// ---------------------------------------------------------------------------
// Kernel 3: a = relu(h @ l0_w^T + l0_b), fp32 out. MFMA 64x64 tiles, K=512.
// Grid (16, 8), 256 threads.
// ---------------------------------------------------------------------------
__global__ __launch_bounds__(256) void k_mlp(
    const __bf16* __restrict__ hfin, const float* __restrict__ l0_w,
    const float* __restrict__ l0_b, float* __restrict__ a_buf)
{
    __shared__ __bf16 As[64 * LKH];
    __shared__ __bf16 Bs[64 * LKH];
    const int i0  = blockIdx.y * 64;
    const int n0  = blockIdx.x * 64;
    const int tid = threadIdx.x;

    {
        const int row = tid >> 2, kq = tid & 3;
        const __bf16* asrc = hfin + (i0 + row) * HH + kq * 128;
        __bf16* adst = &As[row * LKH + kq * 128];
        #pragma unroll
        for (int j = 0; j < 128; j += 8)
            *(uint4*)(adst + j) = *(const uint4*)(asrc + j);
        const float* bsrc = l0_w + (n0 + row) * HH + kq * 128;
        __bf16* bdst = &Bs[row * LKH + kq * 128];
        #pragma unroll
        for (int j = 0; j < 128; j += 4) {
            float4 v = *(const float4*)(bsrc + j);
            bf4 pk = {(__bf16)v.x, (__bf16)v.y, (__bf16)v.z, (__bf16)v.w};
            *(bf4*)(bdst + j) = pk;
        }
    }
    __syncthreads();

    const int wave = tid >> 6, lane = tid & 63;
    const int wm = (wave & 1) * 32, wn = (wave >> 1) * 32;
    const int lr = lane & 15, kk = (lane >> 4) * 8;
    f32x4 acc[2][2] = {};
    #pragma unroll
    for (int kc = 0; kc < 16; ++kc) {
        const int kb = kc * 32 + kk;
        bf16x8 a0 = *(const bf16x8*)(&As[(wm      + lr) * LKH + kb]);
        bf16x8 a1 = *(const bf16x8*)(&As[(wm + 16 + lr) * LKH + kb]);
        bf16x8 b0 = *(const bf16x8*)(&Bs[(wn      + lr) * LKH + kb]);
        bf16x8 b1 = *(const bf16x8*)(&Bs[(wn + 16 + lr) * LKH + kb]);
        acc[0][0] = __builtin_amdgcn_mfma_f32_16x16x32_bf16(a0, b0, acc[0][0], 0, 0, 0);
        acc[0][1] = __builtin_amdgcn_mfma_f32_16x16x32_bf16(a0, b1, acc[0][1], 0, 0, 0);
        acc[1][0] = __builtin_amdgcn_mfma_f32_16x16x32_bf16(a1, b0, acc[1][0], 0, 0, 0);
        acc[1][1] = __builtin_amdgcn_mfma_f32_16x16x32_bf16(a1, b1, acc[1][1], 0, 0, 0);
    }

    const int mrow = (lane >> 4) * 4, ncol = lane & 15;
    #pragma unroll
    for (int ni = 0; ni < 2; ++ni) {
        const int nl = wn + ni * 16 + ncol;
        const float bias = l0_b[n0 + nl];
        #pragma unroll
        for (int mi = 0; mi < 2; ++mi) {
            #pragma unroll
            for (int r = 0; r < 4; ++r) {
                const int ml = wm + mi * 16 + mrow + r;
                a_buf[(i0 + ml) * MLPD + (n0 + nl)] = fmaxf(acc[mi][ni][r] + bias, 0.f);
            }
        }
    }
}

// ---------------------------------------------------------------------------
// Kernel 4: logits = relu(a @ l1_w^T + l1_b); out = log_softmax(logits).
// 16 WGs x 256 threads, 32 rows/WG, 8 threads per row (k-split).
// ---------------------------------------------------------------------------
__global__ __launch_bounds__(256) void k_out(
    const float* __restrict__ a_buf, const float* __restrict__ l1_w,
    const float* __restrict__ l1_b, float* __restrict__ out)
{
    __shared__ float red[32][8][3];
    const int tid = threadIdx.x;
    const int r = tid >> 3, p = tid & 7;
    const int row = blockIdx.x * 32 + r;
    const float* arow = a_buf + row * MLPD + p * 128;
    float pl0 = 0.f, pl1 = 0.f, pl2 = 0.f;
    #pragma unroll 8
    for (int j = 0; j < 128; j += 4) {
        float4 av = *(const float4*)(arow + j);
        float4 w0 = *(const float4*)(l1_w + 0 * MLPD + p * 128 + j);
        float4 w1 = *(const float4*)(l1_w + 1 * MLPD + p * 128 + j);
        float4 w2 = *(const float4*)(l1_w + 2 * MLPD + p * 128 + j);
        pl0 += av.x * w0.x + av.y * w0.y + av.z * w0.z + av.w * w0.w;
        pl1 += av.x * w1.x + av.y * w1.y + av.z * w1.z + av.w * w1.w;
        pl2 += av.x * w2.x + av.y * w2.y + av.z * w2.z + av.w * w2.w;
    }
    red[r][p][0] = pl0; red[r][p][1] = pl1; red[r][p][2] = pl2;
    __syncthreads();
    if (p == 0) {
        float l[3];
        #pragma unroll
        for (int c = 0; c < 3; ++c) {
            float s = 0.f;
            #pragma unroll
            for (int q = 0; q < 8; ++q) s += red[r][q][c];
            s += l1_b[c];
            l[c] = fmaxf(s, 0.f);
        }
        float m = fmaxf(l[0], fmaxf(l[1], l[2]));
        float sum = expf(l[0] - m) + expf(l[1] - m) + expf(l[2] - m);
        float ls = m + logf(sum);
        out[row * CC + 0] = l[0] - ls;
        out[row * CC + 1] = l[1] - ls;
        out[row * CC + 2] = l[2] - ls;
    }
}

// ---------------------------------------------------------------------------
extern "C" void kernel_launch(void* const* d_in, const int* in_sizes, int n_in,
                              void* d_out, int out_size, void* d_ws, size_t ws_size,
                              hipStream_t stream) {
    const int*   x    = (const int*)  d_in[0];
    const int*   len  = (const int*)  d_in[1];
    const float* E    = (const float*)d_in[2];
    const float* W_ih = (const float*)d_in[3];
    const float* b_ih = (const float*)d_in[4];
    const float* W_hh = (const float*)d_in[5];
    const float* b_hh = (const float*)d_in[6];
    const float* l0_w = (const float*)d_in[7];
    const float* l0_b = (const float*)d_in[8];
    const float* l1_w = (const float*)d_in[9];
    const float* l1_b = (const float*)d_in[10];
    float* out = (float*)d_out;

    char* ws = (char*)d_ws;
    // layout: [0,4096) barrier; h0 @4096 (512KB); h1 next; P @2MB (67MB bf16);
    // a_buf @ 2MB+67MB (2MB fp32). Total ~71.3 MB.
    unsigned* bar = (unsigned*)ws;
    __bf16* h0 = (__bf16*)(ws + 4096);
    __bf16* h1 = (__bf16*)(ws + 4096 + 524288);
    __bf16* P  = (__bf16*)(ws + (size_t)(2 << 20));
    float* a_buf = (float*)(ws + (size_t)(2 << 20) + 67108864ull);

    // zero barrier counters + h0/h1 (h0 must start as zeros)
    hipMemsetAsync(ws, 0, 4096 + 2 * 524288, stream);

    dim3 g1(8, 8, 128);
    k_proj<<<g1, 256, 0, stream>>>(x, len, E, W_ih, b_ih, b_hh, P);
    k_rnn<<<256, 256, 0, stream>>>(len, W_hh, P, h0, h1, bar);
    dim3 g3(16, 8);
    k_mlp<<<g3, 256, 0, stream>>>(h0, l0_w, l0_b, a_buf);
    k_out<<<16, 256, 0, stream>>>(a_buf, l1_w, l1_b, out);
}

// Round 2
// 649.836 us; speedup vs baseline: 7.1955x; 7.1955x over previous
//
#include <hip/hip_runtime.h>
#include <hip/hip_bf16.h>
#include <cstdint>

// Problem constants
#define BB 512      // batch
#define TT 128      // time steps
#define VV 50000
#define DD 300      // embed dim
#define HH 512      // hidden
#define MLPD 1024
#define CC 3

typedef __bf16 bf16x8 __attribute__((ext_vector_type(8)));
typedef float  f32x4  __attribute__((ext_vector_type(4)));

struct alignas(8) bf4 { __bf16 x, y, z, w; };

// fast tanh: 1 - 2/(exp(2x)+1). v_exp_f32 + v_rcp_f32, saturates correctly.
__device__ __forceinline__ float ftanh(float x) {
    float e = __expf(2.0f * x);
    return 1.0f - 2.0f * __builtin_amdgcn_rcpf(e + 1.0f);
}

// ---------------------------------------------------------------------------
// Kernel 0: convert W_hh (fp32, row-major [col][k]) to bf16 Wb.
// ---------------------------------------------------------------------------
__global__ __launch_bounds__(256) void k_prep(
    const float* __restrict__ W_hh, __bf16* __restrict__ Wb)
{
    const int i = (blockIdx.x * 256 + threadIdx.x) * 4;
    float4 v = *(const float4*)(W_hh + i);
    bf4 p = {(__bf16)v.x, (__bf16)v.y, (__bf16)v.z, (__bf16)v.w};
    *(bf4*)(Wb + i) = p;
}

// ---------------------------------------------------------------------------
// Kernel 1: P[t,i,:] = E[x[i,T-1-t]] @ W_ih^T + b_ih + b_hh   (bf16 out)
// 64x64 tiles, K=300 padded to 320, MFMA 16x16x32 bf16.
// Grid: (n_tiles=8, i_tiles=8, t=128), 256 threads. Inactive tiles skipped.
// ---------------------------------------------------------------------------
#define LKP 328   // LDS k-stride (320 + 8 pad), bf16 elems

__global__ __launch_bounds__(256) void k_proj(
    const int* __restrict__ x, const int* __restrict__ lengths,
    const float* __restrict__ E, const float* __restrict__ W_ih,
    const float* __restrict__ b_ih, const float* __restrict__ b_hh,
    __bf16* __restrict__ P)
{
    __shared__ __bf16 As[64 * LKP];
    __shared__ __bf16 Bs[64 * LKP];
    __shared__ int lens_s[64];
    __shared__ int skip_s;

    const int t   = blockIdx.z;
    const int i0  = blockIdx.y * 64;
    const int n0  = blockIdx.x * 64;
    const int tid = threadIdx.x;

    if (tid < 64) lens_s[tid] = lengths[i0 + tid];
    __syncthreads();
    if (tid == 0) {
        int mx = 0;
        for (int j = 0; j < 64; ++j) mx = mx > lens_s[j] ? mx : lens_s[j];
        skip_s = (mx <= TT - 1 - t) ? 1 : 0;
    }
    __syncthreads();
    if (skip_s) return;

    {   // stage A (gathered embeddings) and B (W_ih) as bf16, zero-pad K to 320
        const int row = tid >> 2, kq = tid & 3;
        const int tok = x[(i0 + row) * TT + (TT - 1 - t)];
        const float* arow = E + (size_t)tok * DD;
        const float* brow = W_ih + (n0 + row) * DD;
        __bf16* adst = &As[row * LKP];
        __bf16* bdst = &Bs[row * LKP];
        #pragma unroll
        for (int f = 0; f < 20; ++f) {
            const int k = kq * 80 + f * 4;
            float4 av = make_float4(0.f, 0.f, 0.f, 0.f);
            float4 bv = make_float4(0.f, 0.f, 0.f, 0.f);
            if (k < DD) { av = *(const float4*)(arow + k); bv = *(const float4*)(brow + k); }
            bf4 ap = {(__bf16)av.x, (__bf16)av.y, (__bf16)av.z, (__bf16)av.w};
            bf4 bp = {(__bf16)bv.x, (__bf16)bv.y, (__bf16)bv.z, (__bf16)bv.w};
            *(bf4*)(adst + k) = ap;
            *(bf4*)(bdst + k) = bp;
        }
    }
    __syncthreads();

    const int wave = tid >> 6, lane = tid & 63;
    const int wm = (wave & 1) * 32, wn = (wave >> 1) * 32;
    const int lr = lane & 15, kk = (lane >> 4) * 8;
    f32x4 acc[2][2] = {};
    #pragma unroll
    for (int kc = 0; kc < 10; ++kc) {
        const int kb = kc * 32 + kk;
        bf16x8 a0 = *(const bf16x8*)(&As[(wm      + lr) * LKP + kb]);
        bf16x8 a1 = *(const bf16x8*)(&As[(wm + 16 + lr) * LKP + kb]);
        bf16x8 b0 = *(const bf16x8*)(&Bs[(wn      + lr) * LKP + kb]);
        bf16x8 b1 = *(const bf16x8*)(&Bs[(wn + 16 + lr) * LKP + kb]);
        acc[0][0] = __builtin_amdgcn_mfma_f32_16x16x32_bf16(a0, b0, acc[0][0], 0, 0, 0);
        acc[0][1] = __builtin_amdgcn_mfma_f32_16x16x32_bf16(a0, b1, acc[0][1], 0, 0, 0);
        acc[1][0] = __builtin_amdgcn_mfma_f32_16x16x32_bf16(a1, b0, acc[1][0], 0, 0, 0);
        acc[1][1] = __builtin_amdgcn_mfma_f32_16x16x32_bf16(a1, b1, acc[1][1], 0, 0, 0);
    }

    // C/D layout (m89/m91): col = lane&15 (N), row = (lane>>4)*4 + reg (M)
    const int mrow = (lane >> 4) * 4, ncol = lane & 15;
    #pragma unroll
    for (int ni = 0; ni < 2; ++ni) {
        const int nl = wn + ni * 16 + ncol;
        const float bias = b_ih[n0 + nl] + b_hh[n0 + nl];
        #pragma unroll
        for (int mi = 0; mi < 2; ++mi) {
            #pragma unroll
            for (int r = 0; r < 4; ++r) {
                const int ml = wm + mi * 16 + mrow + r;
                P[(t * BB + (i0 + ml)) * HH + (n0 + nl)] = (__bf16)(acc[mi][ni][r] + bias);
            }
        }
    }
}

// ---------------------------------------------------------------------------
// Kernel 2: recurrence, ROW-PARTITIONED (no inter-WG communication at all).
// 32 WGs x 512 threads (8 waves). Each WG owns 16 sample rows; h[16x512]
// lives in LDS for all 128 steps. W_hh resident per CU: cols {w*64..w*64+15}
// for each wave w in LDS (128 cols total), cols {w*64+16..w*64+63} in VGPRs
// (3 coltiles x 16 kc = 192 VGPRs of frags per thread).
// Per step: 2 x __syncthreads, zero global traffic except P reads (16 KB).
// ---------------------------------------------------------------------------
#define LKH 520   // LDS k-stride (512 + 8 pad), bf16 elems

__global__ __launch_bounds__(512, 2) void k_rnn(
    const int* __restrict__ lengths, const __bf16* __restrict__ Wb,
    const __bf16* __restrict__ P, __bf16* __restrict__ h_final)
{
    __shared__ __bf16 Hs[16 * LKH];       // 16.6 KB, hidden state (in-place)
    __shared__ __bf16 Blds[128 * LKH];    // 133.1 KB, W_hh cols (frag tile 0 per wave)
    __shared__ int lens_s[16];

    const int tid = threadIdx.x;
    const int r0  = blockIdx.x * 16;      // this WG's sample rows
    const int w   = tid >> 6;             // wave 0..7
    const int lane = tid & 63;
    const int n = lane & 15, q = lane >> 4;
    const int c0w = w * 64;               // this wave's column range [c0w, c0w+64)

    // ---- prologue: zero Hs, load lens, stage Blds, load Bv frags ----
    for (int i = tid; i < 16 * LKH; i += 512) Hs[i] = (__bf16)0.f;
    if (tid < 16) lens_s[tid] = lengths[r0 + tid];

    // Blds[L][k] holds global col c = (L>>4)*64 + (L&15), L in [0,128)
    for (int idx = tid * 8; idx < 128 * 512; idx += 512 * 8) {
        const int L = idx >> 9, k = idx & 511;
        const int c = (L >> 4) * 64 + (L & 15);
        *(uint4*)(&Blds[L * LKH + k]) = *(const uint4*)(Wb + c * 512 + k);
    }

    // VGPR-resident B frags: coltiles 1..3 of this wave's range.
    // frag layout: lane n+16q holds B[c][kc*32 + q*8 + j], c = c0w + ct*16 + n
    bf16x8 Bv[3][16];
    #pragma unroll
    for (int ct = 0; ct < 3; ++ct) {
        const int c = c0w + (ct + 1) * 16 + n;
        #pragma unroll
        for (int kc = 0; kc < 16; ++kc)
            Bv[ct][kc] = *(const bf16x8*)(Wb + c * 512 + kc * 32 + q * 8);
    }
    __syncthreads();

    // ---- recurrence ----
    for (int t = 0; t < TT; ++t) {
        // prefetch this step's P values (consumed in epilogue; latency hidden
        // behind the MFMA loop). Unwritten P is only read for inactive rows
        // and discarded.
        __bf16 pv[4][4];   // [ct][r]
        #pragma unroll
        for (int ct = 0; ct < 4; ++ct) {
            const int gc = c0w + ct * 16 + n;
            #pragma unroll
            for (int r = 0; r < 4; ++r)
                pv[ct][r] = P[(t * BB + (r0 + q * 4 + r)) * HH + gc];
        }

        f32x4 acc0 = {0.f,0.f,0.f,0.f}, acc1 = {0.f,0.f,0.f,0.f};
        f32x4 acc2 = {0.f,0.f,0.f,0.f}, acc3 = {0.f,0.f,0.f,0.f};
        #pragma unroll
        for (int kc = 0; kc < 16; ++kc) {
            const int kb = kc * 32 + q * 8;
            bf16x8 a  = *(const bf16x8*)(&Hs[n * LKH + kb]);
            bf16x8 bl = *(const bf16x8*)(&Blds[(w * 16 + n) * LKH + kb]);
            acc0 = __builtin_amdgcn_mfma_f32_16x16x32_bf16(a, bl,        acc0, 0, 0, 0);
            acc1 = __builtin_amdgcn_mfma_f32_16x16x32_bf16(a, Bv[0][kc], acc1, 0, 0, 0);
            acc2 = __builtin_amdgcn_mfma_f32_16x16x32_bf16(a, Bv[1][kc], acc2, 0, 0, 0);
            acc3 = __builtin_amdgcn_mfma_f32_16x16x32_bf16(a, Bv[2][kc], acc3, 0, 0, 0);
        }
        __syncthreads();   // all Hs reads done before anyone overwrites

        const int thr = TT - 1 - t;  // token index consumed at step t
        #pragma unroll
        for (int r = 0; r < 4; ++r) {
            const int m = q * 4 + r;                 // C/D layout: row = q*4+reg
            if (thr < lens_s[m]) {
                Hs[m * LKH + c0w +  0 + n] = (__bf16)ftanh(acc0[r] + (float)pv[0][r]);
                Hs[m * LKH + c0w + 16 + n] = (__bf16)ftanh(acc1[r] + (float)pv[1][r]);
                Hs[m * LKH + c0w + 32 + n] = (__bf16)ftanh(acc2[r] + (float)pv[2][r]);
                Hs[m * LKH + c0w + 48 + n] = (__bf16)ftanh(acc3[r] + (float)pv[3][r]);
            }
        }
        __syncthreads();   // writes visible before next step's reads
    }

    // ---- write final h to global ----
    for (int idx = tid * 8; idx < 16 * 512; idx += 512 * 8) {
        const int row = idx >> 9, col = idx & 511;
        *(uint4*)(h_final + (r0 + row) * HH + col) = *(const uint4*)(&Hs[row * LKH + col]);
    }
}

// ---------------------------------------------------------------------------
// Kernel 3: a = relu(h @ l0_w^T + l0_b), fp32 out. MFMA 64x64 tiles, K=512.
// ---------------------------------------------------------------------------
__global__ __launch_bounds__(256) void k_mlp(
    const __bf16* __restrict__ hfin, const float* __restrict__ l0_w,
    const float* __restrict__ l0_b, float* __restrict__ a_buf)
{
    __shared__ __bf16 As[64 * LKH];
    __shared__ __bf16 Bs[64 * LKH];
    const int i0  = blockIdx.y * 64;
    const int n0  = blockIdx.x * 64;
    const int tid = threadIdx.x;

    {
        const int row = tid >> 2, kq = tid & 3;
        const __bf16* asrc = hfin + (i0 + row) * HH + kq * 128;
        __bf16* adst = &As[row * LKH + kq * 128];
        #pragma unroll
        for (int j = 0; j < 128; j += 8)
            *(uint4*)(adst + j) = *(const uint4*)(asrc + j);
        const float* bsrc = l0_w + (n0 + row) * HH + kq * 128;
        __bf16* bdst = &Bs[row * LKH + kq * 128];
        #pragma unroll
        for (int j = 0; j < 128; j += 4) {
            float4 v = *(const float4*)(bsrc + j);
            bf4 pk = {(__bf16)v.x, (__bf16)v.y, (__bf16)v.z, (__bf16)v.w};
            *(bf4*)(bdst + j) = pk;
        }
    }
    __syncthreads();

    const int wave = tid >> 6, lane = tid & 63;
    const int wm = (wave & 1) * 32, wn = (wave >> 1) * 32;
    const int lr = lane & 15, kk = (lane >> 4) * 8;
    f32x4 acc[2][2] = {};
    #pragma unroll
    for (int kc = 0; kc < 16; ++kc) {
        const int kb = kc * 32 + kk;
        bf16x8 a0 = *(const bf16x8*)(&As[(wm      + lr) * LKH + kb]);
        bf16x8 a1 = *(const bf16x8*)(&As[(wm + 16 + lr) * LKH + kb]);
        bf16x8 b0 = *(const bf16x8*)(&Bs[(wn      + lr) * LKH + kb]);
        bf16x8 b1 = *(const bf16x8*)(&Bs[(wn + 16 + lr) * LKH + kb]);
        acc[0][0] = __builtin_amdgcn_mfma_f32_16x16x32_bf16(a0, b0, acc[0][0], 0, 0, 0);
        acc[0][1] = __builtin_amdgcn_mfma_f32_16x16x32_bf16(a0, b1, acc[0][1], 0, 0, 0);
        acc[1][0] = __builtin_amdgcn_mfma_f32_16x16x32_bf16(a1, b0, acc[1][0], 0, 0, 0);
        acc[1][1] = __builtin_amdgcn_mfma_f32_16x16x32_bf16(a1, b1, acc[1][1], 0, 0, 0);
    }

    const int mrow = (lane >> 4) * 4, ncol = lane & 15;
    #pragma unroll
    for (int ni = 0; ni < 2; ++ni) {
        const int nl = wn + ni * 16 + ncol;
        const float bias = l0_b[n0 + nl];
        #pragma unroll
        for (int mi = 0; mi < 2; ++mi) {
            #pragma unroll
            for (int r = 0; r < 4; ++r) {
                const int ml = wm + mi * 16 + mrow + r;
                a_buf[(i0 + ml) * MLPD + (n0 + nl)] = fmaxf(acc[mi][ni][r] + bias, 0.f);
            }
        }
    }
}

// ---------------------------------------------------------------------------
// Kernel 4: logits = relu(a @ l1_w^T + l1_b); out = log_softmax(logits).
// ---------------------------------------------------------------------------
__global__ __launch_bounds__(256) void k_out(
    const float* __restrict__ a_buf, const float* __restrict__ l1_w,
    const float* __restrict__ l1_b, float* __restrict__ out)
{
    __shared__ float red[32][8][3];
    const int tid = threadIdx.x;
    const int r = tid >> 3, p = tid & 7;
    const int row = blockIdx.x * 32 + r;
    const float* arow = a_buf + row * MLPD + p * 128;
    float pl0 = 0.f, pl1 = 0.f, pl2 = 0.f;
    #pragma unroll 8
    for (int j = 0; j < 128; j += 4) {
        float4 av = *(const float4*)(arow + j);
        float4 w0 = *(const float4*)(l1_w + 0 * MLPD + p * 128 + j);
        float4 w1 = *(const float4*)(l1_w + 1 * MLPD + p * 128 + j);
        float4 w2 = *(const float4*)(l1_w + 2 * MLPD + p * 128 + j);
        pl0 += av.x * w0.x + av.y * w0.y + av.z * w0.z + av.w * w0.w;
        pl1 += av.x * w1.x + av.y * w1.y + av.z * w1.z + av.w * w1.w;
        pl2 += av.x * w2.x + av.y * w2.y + av.z * w2.z + av.w * w2.w;
    }
    red[r][p][0] = pl0; red[r][p][1] = pl1; red[r][p][2] = pl2;
    __syncthreads();
    if (p == 0) {
        float l[3];
        #pragma unroll
        for (int c = 0; c < 3; ++c) {
            float s = 0.f;
            #pragma unroll
            for (int qq = 0; qq < 8; ++qq) s += red[r][qq][c];
            s += l1_b[c];
            l[c] = fmaxf(s, 0.f);
        }
        float m = fmaxf(l[0], fmaxf(l[1], l[2]));
        float sum = expf(l[0] - m) + expf(l[1] - m) + expf(l[2] - m);
        float ls = m + logf(sum);
        out[row * CC + 0] = l[0] - ls;
        out[row * CC + 1] = l[1] - ls;
        out[row * CC + 2] = l[2] - ls;
    }
}

// ---------------------------------------------------------------------------
extern "C" void kernel_launch(void* const* d_in, const int* in_sizes, int n_in,
                              void* d_out, int out_size, void* d_ws, size_t ws_size,
                              hipStream_t stream) {
    const int*   x    = (const int*)  d_in[0];
    const int*   len  = (const int*)  d_in[1];
    const float* E    = (const float*)d_in[2];
    const float* W_ih = (const float*)d_in[3];
    const float* b_ih = (const float*)d_in[4];
    const float* W_hh = (const float*)d_in[5];
    const float* b_hh = (const float*)d_in[6];
    const float* l0_w = (const float*)d_in[7];
    const float* l0_b = (const float*)d_in[8];
    const float* l1_w = (const float*)d_in[9];
    const float* l1_b = (const float*)d_in[10];
    float* out = (float*)d_out;

    char* ws = (char*)d_ws;
    // layout: Wb bf16 @0 (512KB); h_final bf16 @512KB (512KB); P @2MB (67MB);
    // a_buf @2MB+67MB (2MB fp32). Everything read is written first -> no memset.
    __bf16* Wb      = (__bf16*)ws;
    __bf16* h_final = (__bf16*)(ws + 524288);
    __bf16* P       = (__bf16*)(ws + (size_t)(2 << 20));
    float*  a_buf   = (float*) (ws + (size_t)(2 << 20) + 67108864ull);

    k_prep<<<256, 256, 0, stream>>>(W_hh, Wb);
    dim3 g1(8, 8, 128);
    k_proj<<<g1, 256, 0, stream>>>(x, len, E, W_ih, b_ih, b_hh, P);
    k_rnn<<<32, 512, 0, stream>>>(len, Wb, P, h_final);
    dim3 g3(16, 8);
    k_mlp<<<g3, 256, 0, stream>>>(h_final, l0_w, l0_b, a_buf);
    k_out<<<16, 256, 0, stream>>>(a_buf, l1_w, l1_b, out);
}

// Round 3
// 639.643 us; speedup vs baseline: 7.3102x; 1.0159x over previous
//
#include <hip/hip_runtime.h>
#include <hip/hip_bf16.h>
#include <cstdint>

// Problem constants
#define BB 512      // batch
#define TT 128      // time steps
#define VV 50000
#define DD 300      // embed dim
#define HH 512      // hidden
#define MLPD 1024
#define CC 3

typedef __bf16 bf16x8 __attribute__((ext_vector_type(8)));
typedef float  f32x4  __attribute__((ext_vector_type(4)));

struct alignas(8)  bf4 { __bf16 x, y, z, w; };

// fast tanh: 1 - 2/(exp(2x)+1). Saturates correctly at +/-1.
__device__ __forceinline__ float ftanh(float x) {
    float e = __expf(2.0f * x);
    return 1.0f - 2.0f * __builtin_amdgcn_rcpf(e + 1.0f);
}

// ---------------------------------------------------------------------------
// k_prep_hh: W_hh (fp32 [c][k]) -> bf16 in MFMA B-frag order.
// Frag b128 #T (T in [0,32768)): lane=T&63, kc=(T>>6)&15, ct=(T>>10)&3,
// w=(T>>12)&7; col c = w*64+ct*16+(lane&15), k = kc*32+(lane>>4)*8.
// k_rnn wave w loads Bv[ct][kc] contiguously at ((w*4+ct)*16+kc)*64+lane.
// ---------------------------------------------------------------------------
__global__ __launch_bounds__(256) void k_prep_hh(
    const float* __restrict__ W, __bf16* __restrict__ out)
{
    const int T = blockIdx.x * 256 + threadIdx.x;    // 0..32767
    const int lane = T & 63;
    const int kc = (T >> 6) & 15;
    const int ct = (T >> 10) & 3;
    const int w  = (T >> 12) & 7;
    const int c = w * 64 + ct * 16 + (lane & 15);
    const int k = kc * 32 + (lane >> 4) * 8;
    const float* src = W + c * HH + k;
    float4 v0 = *(const float4*)src;
    float4 v1 = *(const float4*)(src + 4);
    bf16x8 o;
    o[0]=(__bf16)v0.x; o[1]=(__bf16)v0.y; o[2]=(__bf16)v0.z; o[3]=(__bf16)v0.w;
    o[4]=(__bf16)v1.x; o[5]=(__bf16)v1.y; o[6]=(__bf16)v1.z; o[7]=(__bf16)v1.w;
    *(bf16x8*)(out + (size_t)T * 8) = o;
}

// ---------------------------------------------------------------------------
// k_prep_ih: W_ih (fp32 [c][k], K=300 zero-padded to 320) -> bf16 B-frag order
// for k_proj: b128 #U (U in [0,20480)): lane=U&63, kc=(U>>6)%10,
// g=(U>>6)/10, wp=g&3, nt=g>>2; c = nt*64+wp*16+(lane&15), k = kc*32+(lane>>4)*8.
// ---------------------------------------------------------------------------
__global__ __launch_bounds__(256) void k_prep_ih(
    const float* __restrict__ W, __bf16* __restrict__ out)
{
    const int U = blockIdx.x * 256 + threadIdx.x;    // 0..20479
    const int lane = U & 63;
    const int rest = U >> 6;
    const int kc = rest % 10;
    const int g  = rest / 10;
    const int wp = g & 3, nt = g >> 2;
    const int c = nt * 64 + wp * 16 + (lane & 15);
    const int k = kc * 32 + (lane >> 4) * 8;
    bf16x8 o;
    #pragma unroll
    for (int j = 0; j < 8; ++j) {
        const int kk = k + j;
        o[j] = (__bf16)((kk < DD) ? W[c * DD + kk] : 0.f);
    }
    *(bf16x8*)(out + (size_t)U * 8) = o;
}

// ---------------------------------------------------------------------------
// k_proj: P_c[t] = C-frag-ordered (E[x[i,T-1-t]] @ W_ih^T + b_ih + b_hh).
// Grid (128 t, 8 i-tiles) x 256 thr (4 waves). Embeddings gathered ONCE per
// (tile,t) into frag-layout LDS; A-frags register-resident across the N loop;
// W_ih streamed as pre-fragged bf16 from L2. Inactive rows: zeros staged
// (their P output = bias, discarded by k_rnn anyway).
// P_c flat bf16 index: (((t*32 + wg)*8 + nt)*64 + lane)*16 + wp*4 + r
//   where wg = global_row>>4, lane = n+16q (C-layout), value at row q*4+r.
// ---------------------------------------------------------------------------
__global__ __launch_bounds__(256, 2) void k_proj(
    const int* __restrict__ x, const int* __restrict__ lengths,
    const float* __restrict__ E, const __bf16* __restrict__ Wih,
    const float* __restrict__ b_ih, const float* __restrict__ b_hh,
    __bf16* __restrict__ P_c)
{
    __shared__ __bf16 Afs[40 * 64 * 8];   // 40 chunks (4 ms x 10 kc) -> 40 KB
    __shared__ float bias_s[HH];

    const int t   = blockIdx.x;
    const int i0  = blockIdx.y * 64;
    const int wg0 = blockIdx.y * 4;
    const int tid = threadIdx.x;

    bias_s[tid]       = b_ih[tid]       + b_hh[tid];
    bias_s[tid + 256] = b_ih[tid + 256] + b_hh[tid + 256];

    {   // stage gathered embeddings into A-frag layout (zero for inactive rows)
        const int row = tid >> 2, part = tid & 3;
        const int gr = i0 + row;
        const bool act = (TT - 1 - t) < lengths[gr];
        const float* erow = nullptr;
        if (act) erow = E + (size_t)x[gr * TT + (TT - 1 - t)] * DD;
        const int n15 = row & 15, ms = row >> 4;
        #pragma unroll
        for (int f = 0; f < 20; ++f) {
            const int k = part * 80 + f * 4;
            float4 v = make_float4(0.f, 0.f, 0.f, 0.f);
            if (act && k < DD) v = *(const float4*)(erow + k);
            bf4 pk = {(__bf16)v.x, (__bf16)v.y, (__bf16)v.z, (__bf16)v.w};
            const int chunk = ms * 10 + (k >> 5);
            const int lane_t = n15 + 16 * ((k >> 3) & 3);
            *(bf4*)(&Afs[(chunk * 64 + lane_t) * 8 + (k & 7)]) = pk;
        }
    }
    __syncthreads();

    const int wp = tid >> 6, lane = tid & 63;

    // A-frags to registers (shared across all 8 n-tiles): 160 VGPRs
    bf16x8 Af[4][10];
    #pragma unroll
    for (int ms = 0; ms < 4; ++ms)
        #pragma unroll
        for (int kc = 0; kc < 10; ++kc)
            Af[ms][kc] = *(const bf16x8*)(&Afs[((ms * 10 + kc) * 64 + lane) * 8]);

    for (int nt = 0; nt < 8; ++nt) {
        const __bf16* bbase = Wih + ((size_t)((nt * 4 + wp) * 10) * 64 + lane) * 8;
        bf16x8 Bf[10];
        #pragma unroll
        for (int kc = 0; kc < 10; ++kc)
            Bf[kc] = *(const bf16x8*)(bbase + (size_t)kc * 512);

        f32x4 acc[4] = {};
        #pragma unroll
        for (int kc = 0; kc < 10; ++kc) {
            acc[0] = __builtin_amdgcn_mfma_f32_16x16x32_bf16(Af[0][kc], Bf[kc], acc[0], 0, 0, 0);
            acc[1] = __builtin_amdgcn_mfma_f32_16x16x32_bf16(Af[1][kc], Bf[kc], acc[1], 0, 0, 0);
            acc[2] = __builtin_amdgcn_mfma_f32_16x16x32_bf16(Af[2][kc], Bf[kc], acc[2], 0, 0, 0);
            acc[3] = __builtin_amdgcn_mfma_f32_16x16x32_bf16(Af[3][kc], Bf[kc], acc[3], 0, 0, 0);
        }

        const float bias = bias_s[nt * 64 + wp * 16 + (lane & 15)];
        #pragma unroll
        for (int ms = 0; ms < 4; ++ms) {
            bf4 pk = {(__bf16)(acc[ms][0] + bias), (__bf16)(acc[ms][1] + bias),
                      (__bf16)(acc[ms][2] + bias), (__bf16)(acc[ms][3] + bias)};
            const size_t off = ((size_t)(((t * 32 + wg0 + ms) * 8 + nt) * 64 + lane)) * 16 + wp * 4;
            *(bf4*)(P_c + off) = pk;
        }
    }
}

// ---------------------------------------------------------------------------
// k_rnn: row-partitioned recurrence, LDS-read-minimized.
// 32 WGs x 512 thr (8 waves). Hs in A-FRAG layout (16 chunks x 64 lanes x 16B
// = 16 KB), reads are wave-contiguous 1024B blocks (conflict-free). ALL of
// W_hh's per-wave 64-col slice register-resident (Bv[4][16], 256 regs ->
// AGPRs). Per step per CU: 128 ds_read_b128 (A) + 2 coalesced P loads/lane.
// In-place Hs update (inactive rows untouched = carry), 2 barriers/step.
// ---------------------------------------------------------------------------
__global__ __launch_bounds__(512, 2) void k_rnn(
    const int* __restrict__ lengths, const __bf16* __restrict__ Wb,
    const __bf16* __restrict__ P_c, __bf16* __restrict__ h_final)
{
    __shared__ __bf16 Hs[16 * 64 * 8];    // 16 KB, frag layout

    const int tid = threadIdx.x;
    const int wg  = blockIdx.x;
    const int r0  = wg * 16;
    const int w    = tid >> 6;
    const int lane = tid & 63;
    const int n = lane & 15, q = lane >> 4;

    // zero h
    for (int i = tid * 8; i < 16 * 64 * 8; i += 512 * 8)
        *(bf16x8*)(&Hs[i]) = bf16x8{};

    // per-lane lengths for rows m = q*4+r
    int lens_v[4];
    #pragma unroll
    for (int r = 0; r < 4; ++r) lens_v[r] = lengths[r0 + q * 4 + r];

    // W_hh slice into registers (frag-ordered -> contiguous loads)
    bf16x8 Bv[4][16];
    #pragma unroll
    for (int ct = 0; ct < 4; ++ct)
        #pragma unroll
        for (int kc = 0; kc < 16; ++kc)
            Bv[ct][kc] = *(const bf16x8*)(Wb + ((size_t)(((w * 4 + ct) * 16 + kc) * 64) + lane) * 8);

    __syncthreads();

    const __bf16* pcb = P_c + ((size_t)(wg * 8 + w) * 64 + lane) * 16;

    for (int t = 0; t < TT; ++t) {
        // P for this step: 2 coalesced 16B loads (C-frag order), hidden by MFMA
        bf16x8 pva = *(const bf16x8*)(pcb + (size_t)t * 262144);
        bf16x8 pvb = *(const bf16x8*)(pcb + (size_t)t * 262144 + 8);

        f32x4 acc0 = {}, acc1 = {}, acc2 = {}, acc3 = {};
        #pragma unroll
        for (int kc = 0; kc < 16; ++kc) {
            bf16x8 a = *(const bf16x8*)(&Hs[kc * 512 + lane * 8]);
            acc0 = __builtin_amdgcn_mfma_f32_16x16x32_bf16(a, Bv[0][kc], acc0, 0, 0, 0);
            acc1 = __builtin_amdgcn_mfma_f32_16x16x32_bf16(a, Bv[1][kc], acc1, 0, 0, 0);
            acc2 = __builtin_amdgcn_mfma_f32_16x16x32_bf16(a, Bv[2][kc], acc2, 0, 0, 0);
            acc3 = __builtin_amdgcn_mfma_f32_16x16x32_bf16(a, Bv[3][kc], acc3, 0, 0, 0);
        }
        __syncthreads();   // all Hs reads complete before in-place writes

        const int thr = TT - 1 - t;
        #pragma unroll
        for (int ct = 0; ct < 4; ++ct) {
            const int c = w * 64 + ct * 16 + n;         // global hidden col
            const int kc_t = c >> 5, q_t = (c >> 3) & 3, j = c & 7;
            const f32x4& ac = (ct == 0) ? acc0 : (ct == 1) ? acc1 : (ct == 2) ? acc2 : acc3;
            #pragma unroll
            for (int r = 0; r < 4; ++r) {
                if (thr < lens_v[r]) {                  // inactive rows: carry (no write)
                    const int idx = ct * 4 + r;
                    const float pvf = (float)((idx < 8) ? pva[idx] : pvb[idx - 8]);
                    const float hv = ftanh(ac[r] + pvf);
                    const int lt = q * 4 + r + 16 * q_t;
                    Hs[(kc_t * 64 + lt) * 8 + j] = (__bf16)hv;
                }
            }
        }
        __syncthreads();   // writes visible before next step's reads
    }

    // drain: frag layout -> row-major h_final
    for (int idx = tid; idx < 16 * 64; idx += 512) {
        const int kc = idx >> 6, l = idx & 63;
        bf16x8 vv = *(const bf16x8*)(&Hs[(kc * 64 + l) * 8]);
        *(bf16x8*)(h_final + (size_t)(r0 + (l & 15)) * HH + kc * 32 + (l >> 4) * 8) = vv;
    }
}

// ---------------------------------------------------------------------------
// k_mlp: a = relu(h @ l0_w^T + l0_b), fp32 out. 64x64 tiles, K=512.
// ---------------------------------------------------------------------------
#define LKH 520

__global__ __launch_bounds__(256) void k_mlp(
    const __bf16* __restrict__ hfin, const float* __restrict__ l0_w,
    const float* __restrict__ l0_b, float* __restrict__ a_buf)
{
    __shared__ __bf16 As[64 * LKH];
    __shared__ __bf16 Bs[64 * LKH];
    const int i0  = blockIdx.y * 64;
    const int n0  = blockIdx.x * 64;
    const int tid = threadIdx.x;

    {
        const int row = tid >> 2, kq = tid & 3;
        const __bf16* asrc = hfin + (i0 + row) * HH + kq * 128;
        __bf16* adst = &As[row * LKH + kq * 128];
        #pragma unroll
        for (int j = 0; j < 128; j += 8)
            *(uint4*)(adst + j) = *(const uint4*)(asrc + j);
        const float* bsrc = l0_w + (n0 + row) * HH + kq * 128;
        __bf16* bdst = &Bs[row * LKH + kq * 128];
        #pragma unroll
        for (int j = 0; j < 128; j += 4) {
            float4 v = *(const float4*)(bsrc + j);
            bf4 pk = {(__bf16)v.x, (__bf16)v.y, (__bf16)v.z, (__bf16)v.w};
            *(bf4*)(bdst + j) = pk;
        }
    }
    __syncthreads();

    const int wave = tid >> 6, lane = tid & 63;
    const int wm = (wave & 1) * 32, wn = (wave >> 1) * 32;
    const int lr = lane & 15, kk = (lane >> 4) * 8;
    f32x4 acc[2][2] = {};
    #pragma unroll
    for (int kc = 0; kc < 16; ++kc) {
        const int kb = kc * 32 + kk;
        bf16x8 a0 = *(const bf16x8*)(&As[(wm      + lr) * LKH + kb]);
        bf16x8 a1 = *(const bf16x8*)(&As[(wm + 16 + lr) * LKH + kb]);
        bf16x8 b0 = *(const bf16x8*)(&Bs[(wn      + lr) * LKH + kb]);
        bf16x8 b1 = *(const bf16x8*)(&Bs[(wn + 16 + lr) * LKH + kb]);
        acc[0][0] = __builtin_amdgcn_mfma_f32_16x16x32_bf16(a0, b0, acc[0][0], 0, 0, 0);
        acc[0][1] = __builtin_amdgcn_mfma_f32_16x16x32_bf16(a0, b1, acc[0][1], 0, 0, 0);
        acc[1][0] = __builtin_amdgcn_mfma_f32_16x16x32_bf16(a1, b0, acc[1][0], 0, 0, 0);
        acc[1][1] = __builtin_amdgcn_mfma_f32_16x16x32_bf16(a1, b1, acc[1][1], 0, 0, 0);
    }

    const int mrow = (lane >> 4) * 4, ncol = lane & 15;
    #pragma unroll
    for (int ni = 0; ni < 2; ++ni) {
        const int nl = wn + ni * 16 + ncol;
        const float bias = l0_b[n0 + nl];
        #pragma unroll
        for (int mi = 0; mi < 2; ++mi) {
            #pragma unroll
            for (int r = 0; r < 4; ++r) {
                const int ml = wm + mi * 16 + mrow + r;
                a_buf[(i0 + ml) * MLPD + (n0 + nl)] = fmaxf(acc[mi][ni][r] + bias, 0.f);
            }
        }
    }
}

// ---------------------------------------------------------------------------
// k_out: logits = relu(a @ l1_w^T + l1_b); out = log_softmax(logits).
// ---------------------------------------------------------------------------
__global__ __launch_bounds__(256) void k_out(
    const float* __restrict__ a_buf, const float* __restrict__ l1_w,
    const float* __restrict__ l1_b, float* __restrict__ out)
{
    __shared__ float red[32][8][3];
    const int tid = threadIdx.x;
    const int r = tid >> 3, p = tid & 7;
    const int row = blockIdx.x * 32 + r;
    const float* arow = a_buf + row * MLPD + p * 128;
    float pl0 = 0.f, pl1 = 0.f, pl2 = 0.f;
    #pragma unroll 8
    for (int j = 0; j < 128; j += 4) {
        float4 av = *(const float4*)(arow + j);
        float4 w0 = *(const float4*)(l1_w + 0 * MLPD + p * 128 + j);
        float4 w1 = *(const float4*)(l1_w + 1 * MLPD + p * 128 + j);
        float4 w2 = *(const float4*)(l1_w + 2 * MLPD + p * 128 + j);
        pl0 += av.x * w0.x + av.y * w0.y + av.z * w0.z + av.w * w0.w;
        pl1 += av.x * w1.x + av.y * w1.y + av.z * w1.z + av.w * w1.w;
        pl2 += av.x * w2.x + av.y * w2.y + av.z * w2.z + av.w * w2.w;
    }
    red[r][p][0] = pl0; red[r][p][1] = pl1; red[r][p][2] = pl2;
    __syncthreads();
    if (p == 0) {
        float l[3];
        #pragma unroll
        for (int c = 0; c < 3; ++c) {
            float s = 0.f;
            #pragma unroll
            for (int qq = 0; qq < 8; ++qq) s += red[r][qq][c];
            s += l1_b[c];
            l[c] = fmaxf(s, 0.f);
        }
        float m = fmaxf(l[0], fmaxf(l[1], l[2]));
        float sum = expf(l[0] - m) + expf(l[1] - m) + expf(l[2] - m);
        float ls = m + logf(sum);
        out[row * CC + 0] = l[0] - ls;
        out[row * CC + 1] = l[1] - ls;
        out[row * CC + 2] = l[2] - ls;
    }
}

// ---------------------------------------------------------------------------
extern "C" void kernel_launch(void* const* d_in, const int* in_sizes, int n_in,
                              void* d_out, int out_size, void* d_ws, size_t ws_size,
                              hipStream_t stream) {
    const int*   x    = (const int*)  d_in[0];
    const int*   len  = (const int*)  d_in[1];
    const float* E    = (const float*)d_in[2];
    const float* W_ih = (const float*)d_in[3];
    const float* b_ih = (const float*)d_in[4];
    const float* W_hh = (const float*)d_in[5];
    const float* b_hh = (const float*)d_in[6];
    const float* l0_w = (const float*)d_in[7];
    const float* l0_b = (const float*)d_in[8];
    const float* l1_w = (const float*)d_in[9];
    const float* l1_b = (const float*)d_in[10];
    float* out = (float*)d_out;

    char* ws = (char*)d_ws;
    // layout: Wb_frag @0 (512KB); Wih_frag @512KB (320KB); h_final @1MB
    // (512KB); P_c @2MB (32MB); a_buf @34MB (2MB). Total ~36MB.
    __bf16* Wb    = (__bf16*)ws;
    __bf16* Wih   = (__bf16*)(ws + 524288);
    __bf16* hfin  = (__bf16*)(ws + 1048576);
    __bf16* P_c   = (__bf16*)(ws + 2097152);
    float*  a_buf = (float*) (ws + 2097152 + 33554432ull);

    k_prep_hh<<<128, 256, 0, stream>>>(W_hh, Wb);
    k_prep_ih<<<80, 256, 0, stream>>>(W_ih, Wih);
    dim3 g1(128, 8);
    k_proj<<<g1, 256, 0, stream>>>(x, len, E, Wih, b_ih, b_hh, P_c);
    k_rnn<<<32, 512, 0, stream>>>(len, Wb, P_c, hfin);
    dim3 g3(16, 8);
    k_mlp<<<g3, 256, 0, stream>>>(hfin, l0_w, l0_b, a_buf);
    k_out<<<16, 256, 0, stream>>>(a_buf, l1_w, l1_b, out);
}

// Round 4
// 394.138 us; speedup vs baseline: 11.8636x; 1.6229x over previous
//
#include <hip/hip_runtime.h>
#include <hip/hip_bf16.h>
#include <cstdint>

// Problem constants
#define BB 512      // batch
#define TT 128      // time steps
#define VV 50000
#define DD 300      // embed dim
#define HH 512      // hidden
#define MLPD 1024
#define CC 3

typedef __bf16 bf16x8 __attribute__((ext_vector_type(8)));
typedef float  f32x4  __attribute__((ext_vector_type(4)));
typedef int    v8i    __attribute__((ext_vector_type(8)));

struct alignas(8)  bf4 { __bf16 x, y, z, w; };

// fast tanh: 1 - 2/(exp(2x)+1). Saturates correctly at +/-1.
__device__ __forceinline__ float ftanh(float x) {
    float e = __expf(2.0f * x);
    return 1.0f - 2.0f * __builtin_amdgcn_rcpf(e + 1.0f);
}

// e8m0 scale bytes: value = 2^(E-127). A: h stored x16 -> scale 2^-4 (E=123).
// B: W stored x8 -> scale 2^-3 (E=124).
#define SCALE_A 0x7B7B7B7B
#define SCALE_B 0x7C7C7C7C

// ---------------------------------------------------------------------------
// k_prep_hh8: W_hh (fp32 [c][k]) -> fp8 e4m3 (x8) in MFMA B-frag order for
// 16x16x128: frag F = ((w*4+ct)*4+kch)*64 + lane (32 B each);
// lane = n + 16q holds B[c = w*64+ct*16+n][k = kch*128 + q*32 + j], j=0..31.
// ---------------------------------------------------------------------------
__global__ __launch_bounds__(256) void k_prep_hh8(
    const float* __restrict__ W, unsigned char* __restrict__ out)
{
    const int T = blockIdx.x * 256 + threadIdx.x;    // 0..8191
    const int lane = T & 63;
    const int kch = (T >> 6) & 3;
    const int ct  = (T >> 8) & 3;
    const int w   = (T >> 10) & 7;
    const int n = lane & 15, q = lane >> 4;
    const int c  = w * 64 + ct * 16 + n;
    const int k0 = kch * 128 + q * 32;
    const float* src = W + c * HH + k0;
    unsigned int wd[8];
    #pragma unroll
    for (int i = 0; i < 8; ++i) {
        float4 v = *(const float4*)(src + i * 4);
        unsigned int t0 = __builtin_amdgcn_cvt_pk_fp8_f32(v.x * 8.f, v.y * 8.f, 0, false);
        t0 = __builtin_amdgcn_cvt_pk_fp8_f32(v.z * 8.f, v.w * 8.f, t0, true);
        wd[i] = t0;
    }
    *(uint4*)(out + (size_t)T * 32)      = make_uint4(wd[0], wd[1], wd[2], wd[3]);
    *(uint4*)(out + (size_t)T * 32 + 16) = make_uint4(wd[4], wd[5], wd[6], wd[7]);
}

// ---------------------------------------------------------------------------
// k_prep_ih: W_ih (fp32 [c][k], K=300 zero-padded to 320) -> bf16 B-frag order
// for k_proj (16x16x32): b128 #U: lane=U&63, kc=(U>>6)%10, g=(U>>6)/10,
// wp=g&3, nt=g>>2; c = nt*64+wp*16+(lane&15), k = kc*32+(lane>>4)*8.
// ---------------------------------------------------------------------------
__global__ __launch_bounds__(256) void k_prep_ih(
    const float* __restrict__ W, __bf16* __restrict__ out)
{
    const int U = blockIdx.x * 256 + threadIdx.x;    // 0..20479
    const int lane = U & 63;
    const int rest = U >> 6;
    const int kc = rest % 10;
    const int g  = rest / 10;
    const int wp = g & 3, nt = g >> 2;
    const int c = nt * 64 + wp * 16 + (lane & 15);
    const int k = kc * 32 + (lane >> 4) * 8;
    bf16x8 o;
    #pragma unroll
    for (int j = 0; j < 8; ++j) {
        const int kk = k + j;
        o[j] = (__bf16)((kk < DD) ? W[c * DD + kk] : 0.f);
    }
    *(bf16x8*)(out + (size_t)U * 8) = o;
}

// ---------------------------------------------------------------------------
// k_proj: P_c[t] = C-frag-ordered (E[x[i,T-1-t]] @ W_ih^T + b_ih + b_hh).
// Grid (128 t, 8 i-tiles) x 256 thr (4 waves). Unchanged from round 3.
// P_c flat bf16 index: (((t*32 + wg)*8 + nt)*64 + lane)*16 + wp*4 + r
// ---------------------------------------------------------------------------
__global__ __launch_bounds__(256, 2) void k_proj(
    const int* __restrict__ x, const int* __restrict__ lengths,
    const float* __restrict__ E, const __bf16* __restrict__ Wih,
    const float* __restrict__ b_ih, const float* __restrict__ b_hh,
    __bf16* __restrict__ P_c)
{
    __shared__ __bf16 Afs[40 * 64 * 8];   // 40 KB
    __shared__ float bias_s[HH];

    const int t   = blockIdx.x;
    const int i0  = blockIdx.y * 64;
    const int wg0 = blockIdx.y * 4;
    const int tid = threadIdx.x;

    bias_s[tid]       = b_ih[tid]       + b_hh[tid];
    bias_s[tid + 256] = b_ih[tid + 256] + b_hh[tid + 256];

    {   // stage gathered embeddings into A-frag layout (zero for inactive rows)
        const int row = tid >> 2, part = tid & 3;
        const int gr = i0 + row;
        const bool act = (TT - 1 - t) < lengths[gr];
        const float* erow = nullptr;
        if (act) erow = E + (size_t)x[gr * TT + (TT - 1 - t)] * DD;
        const int n15 = row & 15, ms = row >> 4;
        #pragma unroll
        for (int f = 0; f < 20; ++f) {
            const int k = part * 80 + f * 4;
            float4 v = make_float4(0.f, 0.f, 0.f, 0.f);
            if (act && k < DD) v = *(const float4*)(erow + k);
            bf4 pk = {(__bf16)v.x, (__bf16)v.y, (__bf16)v.z, (__bf16)v.w};
            const int chunk = ms * 10 + (k >> 5);
            const int lane_t = n15 + 16 * ((k >> 3) & 3);
            *(bf4*)(&Afs[(chunk * 64 + lane_t) * 8 + (k & 7)]) = pk;
        }
    }
    __syncthreads();

    const int wp = tid >> 6, lane = tid & 63;

    bf16x8 Af[4][10];
    #pragma unroll
    for (int ms = 0; ms < 4; ++ms)
        #pragma unroll
        for (int kc = 0; kc < 10; ++kc)
            Af[ms][kc] = *(const bf16x8*)(&Afs[((ms * 10 + kc) * 64 + lane) * 8]);

    for (int nt = 0; nt < 8; ++nt) {
        const __bf16* bbase = Wih + ((size_t)((nt * 4 + wp) * 10) * 64 + lane) * 8;
        bf16x8 Bf[10];
        #pragma unroll
        for (int kc = 0; kc < 10; ++kc)
            Bf[kc] = *(const bf16x8*)(bbase + (size_t)kc * 512);

        f32x4 acc[4] = {};
        #pragma unroll
        for (int kc = 0; kc < 10; ++kc) {
            acc[0] = __builtin_amdgcn_mfma_f32_16x16x32_bf16(Af[0][kc], Bf[kc], acc[0], 0, 0, 0);
            acc[1] = __builtin_amdgcn_mfma_f32_16x16x32_bf16(Af[1][kc], Bf[kc], acc[1], 0, 0, 0);
            acc[2] = __builtin_amdgcn_mfma_f32_16x16x32_bf16(Af[2][kc], Bf[kc], acc[2], 0, 0, 0);
            acc[3] = __builtin_amdgcn_mfma_f32_16x16x32_bf16(Af[3][kc], Bf[kc], acc[3], 0, 0, 0);
        }

        const float bias = bias_s[nt * 64 + wp * 16 + (lane & 15)];
        #pragma unroll
        for (int ms = 0; ms < 4; ++ms) {
            bf4 pk = {(__bf16)(acc[ms][0] + bias), (__bf16)(acc[ms][1] + bias),
                      (__bf16)(acc[ms][2] + bias), (__bf16)(acc[ms][3] + bias)};
            const size_t off = ((size_t)(((t * 32 + wg0 + ms) * 8 + nt) * 64 + lane)) * 16 + wp * 4;
            *(bf4*)(P_c + off) = pk;
        }
    }
}

// ---------------------------------------------------------------------------
// k_rnn: fp8-MX recurrence. 32 WGs x 512 thr (8 waves, 2/SIMD).
// W_hh: fp8 (x8), ENTIRE 64-col wave slice in registers (128 VGPRs, no LDS,
// no spill). h: fp8 (x16) in LDS A-frag layout for 16x16x128 (8 KB):
// element (m,c) at byte ((c>>7)*64 + m + 16*((c>>5)&3))*32 + (c&31).
// MFMA: mfma_scale_f32_16x16x128_f8f6f4, scales 2^-4 (A) x 2^-3 (B).
// Per wave per step: 8 ds_read_b128 (A) + 16 MFMA + 16 b8 scatter writes.
// P (bf16, accurate) added pre-tanh in fp32. Inactive rows: no write (carry).
// ---------------------------------------------------------------------------
__global__ __launch_bounds__(512, 2) void k_rnn(
    const int* __restrict__ lengths, const unsigned char* __restrict__ Wb8,
    const __bf16* __restrict__ P_c, __bf16* __restrict__ h_final)
{
    __shared__ unsigned char Hs8[8192];

    const int tid = threadIdx.x;
    const int wg  = blockIdx.x;
    const int r0  = wg * 16;
    const int w    = tid >> 6;
    const int lane = tid & 63;
    const int n = lane & 15, q = lane >> 4;

    // zero h (fp8 0x00 == 0.0)
    for (int i = tid * 16; i < 8192; i += 512 * 16)
        *(uint4*)(&Hs8[i]) = make_uint4(0u, 0u, 0u, 0u);

    int lens_v[4];
    #pragma unroll
    for (int r = 0; r < 4; ++r) lens_v[r] = lengths[r0 + q * 4 + r];

    // whole 64-col W slice -> registers (128 VGPRs)
    v8i Bv[4][4];
    #pragma unroll
    for (int ct = 0; ct < 4; ++ct)
        #pragma unroll
        for (int kch = 0; kch < 4; ++kch)
            Bv[ct][kch] = *(const v8i*)(Wb8 + ((size_t)(((w * 4 + ct) * 4 + kch) * 64 + lane)) * 32);

    __syncthreads();

    const __bf16* pcb = P_c + ((size_t)(wg * 8 + w) * 64 + lane) * 16;

    for (int t = 0; t < TT; ++t) {
        bf16x8 pva = *(const bf16x8*)(pcb + (size_t)t * 262144);
        bf16x8 pvb = *(const bf16x8*)(pcb + (size_t)t * 262144 + 8);

        f32x4 acc[4] = {};
        #pragma unroll
        for (int kch = 0; kch < 4; ++kch) {
            v8i a = *(const v8i*)(&Hs8[(kch * 64 + lane) * 32]);
            acc[0] = __builtin_amdgcn_mfma_scale_f32_16x16x128_f8f6f4(
                         a, Bv[0][kch], acc[0], 0, 0, 0, SCALE_A, 0, SCALE_B);
            acc[1] = __builtin_amdgcn_mfma_scale_f32_16x16x128_f8f6f4(
                         a, Bv[1][kch], acc[1], 0, 0, 0, SCALE_A, 0, SCALE_B);
            acc[2] = __builtin_amdgcn_mfma_scale_f32_16x16x128_f8f6f4(
                         a, Bv[2][kch], acc[2], 0, 0, 0, SCALE_A, 0, SCALE_B);
            acc[3] = __builtin_amdgcn_mfma_scale_f32_16x16x128_f8f6f4(
                         a, Bv[3][kch], acc[3], 0, 0, 0, SCALE_A, 0, SCALE_B);
        }
        __syncthreads();   // all Hs8 reads complete before in-place writes

        const int thr = TT - 1 - t;
        #pragma unroll
        for (int ct = 0; ct < 4; ++ct) {
            // col c = w*64 + ct*16 + n
            const int kch_w = (4 * w + ct) >> 3;
            const int qp    = (2 * w + (ct >> 1)) & 3;
            const int jb    = 16 * (ct & 1) + n;
            #pragma unroll
            for (int r = 0; r < 4; ++r) {
                if (thr < lens_v[r]) {                 // inactive: carry (no write)
                    const int idx = ct * 4 + r;
                    const float pvf = (float)((idx < 8) ? pva[idx] : pvb[idx - 8]);
                    const float hv = ftanh(acc[ct][r] + pvf);
                    const unsigned int pw =
                        __builtin_amdgcn_cvt_pk_fp8_f32(hv * 16.f, hv * 16.f, 0u, false);
                    Hs8[(kch_w * 64 + q * 4 + r + 16 * qp) * 32 + jb] = (unsigned char)(pw & 0xffu);
                }
            }
        }
        __syncthreads();   // writes visible before next step's reads
    }

    // drain: fp8 frag layout -> bf16 row-major h_final (each thread 16 bytes)
    {
        const int half   = tid & 1;
        const int lane_t = (tid >> 1) & 63;
        const int kch    = tid >> 7;
        const int m  = lane_t & 15, qq = lane_t >> 4;
        const int cb = kch * 128 + qq * 32 + half * 16;
        uint4 wv = *(const uint4*)(&Hs8[(kch * 64 + lane_t) * 32 + half * 16]);
        unsigned int ws4[4] = {wv.x, wv.y, wv.z, wv.w};
        bf16x8 o0, o1;
        #pragma unroll
        for (int wd = 0; wd < 4; ++wd) {
            float f0 = __builtin_amdgcn_cvt_f32_fp8(ws4[wd], 0) * 0.0625f;
            float f1 = __builtin_amdgcn_cvt_f32_fp8(ws4[wd], 1) * 0.0625f;
            float f2 = __builtin_amdgcn_cvt_f32_fp8(ws4[wd], 2) * 0.0625f;
            float f3 = __builtin_amdgcn_cvt_f32_fp8(ws4[wd], 3) * 0.0625f;
            if (wd < 2) {
                o0[wd * 4 + 0] = (__bf16)f0; o0[wd * 4 + 1] = (__bf16)f1;
                o0[wd * 4 + 2] = (__bf16)f2; o0[wd * 4 + 3] = (__bf16)f3;
            } else {
                o1[(wd - 2) * 4 + 0] = (__bf16)f0; o1[(wd - 2) * 4 + 1] = (__bf16)f1;
                o1[(wd - 2) * 4 + 2] = (__bf16)f2; o1[(wd - 2) * 4 + 3] = (__bf16)f3;
            }
        }
        *(bf16x8*)(h_final + (size_t)(r0 + m) * HH + cb)     = o0;
        *(bf16x8*)(h_final + (size_t)(r0 + m) * HH + cb + 8) = o1;
    }
}

// ---------------------------------------------------------------------------
// k_mlp: a = relu(h @ l0_w^T + l0_b), fp32 out. 64x64 tiles, K=512.
// ---------------------------------------------------------------------------
#define LKH 520

__global__ __launch_bounds__(256) void k_mlp(
    const __bf16* __restrict__ hfin, const float* __restrict__ l0_w,
    const float* __restrict__ l0_b, float* __restrict__ a_buf)
{
    __shared__ __bf16 As[64 * LKH];
    __shared__ __bf16 Bs[64 * LKH];
    const int i0  = blockIdx.y * 64;
    const int n0  = blockIdx.x * 64;
    const int tid = threadIdx.x;

    {
        const int row = tid >> 2, kq = tid & 3;
        const __bf16* asrc = hfin + (i0 + row) * HH + kq * 128;
        __bf16* adst = &As[row * LKH + kq * 128];
        #pragma unroll
        for (int j = 0; j < 128; j += 8)
            *(uint4*)(adst + j) = *(const uint4*)(asrc + j);
        const float* bsrc = l0_w + (n0 + row) * HH + kq * 128;
        __bf16* bdst = &Bs[row * LKH + kq * 128];
        #pragma unroll
        for (int j = 0; j < 128; j += 4) {
            float4 v = *(const float4*)(bsrc + j);
            bf4 pk = {(__bf16)v.x, (__bf16)v.y, (__bf16)v.z, (__bf16)v.w};
            *(bf4*)(bdst + j) = pk;
        }
    }
    __syncthreads();

    const int wave = tid >> 6, lane = tid & 63;
    const int wm = (wave & 1) * 32, wn = (wave >> 1) * 32;
    const int lr = lane & 15, kk = (lane >> 4) * 8;
    f32x4 acc[2][2] = {};
    #pragma unroll
    for (int kc = 0; kc < 16; ++kc) {
        const int kb = kc * 32 + kk;
        bf16x8 a0 = *(const bf16x8*)(&As[(wm      + lr) * LKH + kb]);
        bf16x8 a1 = *(const bf16x8*)(&As[(wm + 16 + lr) * LKH + kb]);
        bf16x8 b0 = *(const bf16x8*)(&Bs[(wn      + lr) * LKH + kb]);
        bf16x8 b1 = *(const bf16x8*)(&Bs[(wn + 16 + lr) * LKH + kb]);
        acc[0][0] = __builtin_amdgcn_mfma_f32_16x16x32_bf16(a0, b0, acc[0][0], 0, 0, 0);
        acc[0][1] = __builtin_amdgcn_mfma_f32_16x16x32_bf16(a0, b1, acc[0][1], 0, 0, 0);
        acc[1][0] = __builtin_amdgcn_mfma_f32_16x16x32_bf16(a1, b0, acc[1][0], 0, 0, 0);
        acc[1][1] = __builtin_amdgcn_mfma_f32_16x16x32_bf16(a1, b1, acc[1][1], 0, 0, 0);
    }

    const int mrow = (lane >> 4) * 4, ncol = lane & 15;
    #pragma unroll
    for (int ni = 0; ni < 2; ++ni) {
        const int nl = wn + ni * 16 + ncol;
        const float bias = l0_b[n0 + nl];
        #pragma unroll
        for (int mi = 0; mi < 2; ++mi) {
            #pragma unroll
            for (int r = 0; r < 4; ++r) {
                const int ml = wm + mi * 16 + mrow + r;
                a_buf[(i0 + ml) * MLPD + (n0 + nl)] = fmaxf(acc[mi][ni][r] + bias, 0.f);
            }
        }
    }
}

// ---------------------------------------------------------------------------
// k_out: logits = relu(a @ l1_w^T + l1_b); out = log_softmax(logits).
// ---------------------------------------------------------------------------
__global__ __launch_bounds__(256) void k_out(
    const float* __restrict__ a_buf, const float* __restrict__ l1_w,
    const float* __restrict__ l1_b, float* __restrict__ out)
{
    __shared__ float red[32][8][3];
    const int tid = threadIdx.x;
    const int r = tid >> 3, p = tid & 7;
    const int row = blockIdx.x * 32 + r;
    const float* arow = a_buf + row * MLPD + p * 128;
    float pl0 = 0.f, pl1 = 0.f, pl2 = 0.f;
    #pragma unroll 8
    for (int j = 0; j < 128; j += 4) {
        float4 av = *(const float4*)(arow + j);
        float4 w0 = *(const float4*)(l1_w + 0 * MLPD + p * 128 + j);
        float4 w1 = *(const float4*)(l1_w + 1 * MLPD + p * 128 + j);
        float4 w2 = *(const float4*)(l1_w + 2 * MLPD + p * 128 + j);
        pl0 += av.x * w0.x + av.y * w0.y + av.z * w0.z + av.w * w0.w;
        pl1 += av.x * w1.x + av.y * w1.y + av.z * w1.z + av.w * w1.w;
        pl2 += av.x * w2.x + av.y * w2.y + av.z * w2.z + av.w * w2.w;
    }
    red[r][p][0] = pl0; red[r][p][1] = pl1; red[r][p][2] = pl2;
    __syncthreads();
    if (p == 0) {
        float l[3];
        #pragma unroll
        for (int c = 0; c < 3; ++c) {
            float s = 0.f;
            #pragma unroll
            for (int qq = 0; qq < 8; ++qq) s += red[r][qq][c];
            s += l1_b[c];
            l[c] = fmaxf(s, 0.f);
        }
        float m = fmaxf(l[0], fmaxf(l[1], l[2]));
        float sum = expf(l[0] - m) + expf(l[1] - m) + expf(l[2] - m);
        float ls = m + logf(sum);
        out[row * CC + 0] = l[0] - ls;
        out[row * CC + 1] = l[1] - ls;
        out[row * CC + 2] = l[2] - ls;
    }
}

// ---------------------------------------------------------------------------
extern "C" void kernel_launch(void* const* d_in, const int* in_sizes, int n_in,
                              void* d_out, int out_size, void* d_ws, size_t ws_size,
                              hipStream_t stream) {
    const int*   x    = (const int*)  d_in[0];
    const int*   len  = (const int*)  d_in[1];
    const float* E    = (const float*)d_in[2];
    const float* W_ih = (const float*)d_in[3];
    const float* b_ih = (const float*)d_in[4];
    const float* W_hh = (const float*)d_in[5];
    const float* b_hh = (const float*)d_in[6];
    const float* l0_w = (const float*)d_in[7];
    const float* l0_b = (const float*)d_in[8];
    const float* l1_w = (const float*)d_in[9];
    const float* l1_b = (const float*)d_in[10];
    float* out = (float*)d_out;

    char* ws = (char*)d_ws;
    // layout: Wb8 fp8 @0 (256KB); Wih_frag @512KB (320KB); h_final @1MB
    // (512KB); P_c @2MB (32MB); a_buf @34MB (2MB).
    unsigned char* Wb8 = (unsigned char*)ws;
    __bf16* Wih   = (__bf16*)(ws + 524288);
    __bf16* hfin  = (__bf16*)(ws + 1048576);
    __bf16* P_c   = (__bf16*)(ws + 2097152);
    float*  a_buf = (float*) (ws + 2097152 + 33554432ull);

    k_prep_hh8<<<32, 256, 0, stream>>>(W_hh, Wb8);
    k_prep_ih<<<80, 256, 0, stream>>>(W_ih, Wih);
    dim3 g1(128, 8);
    k_proj<<<g1, 256, 0, stream>>>(x, len, E, Wih, b_ih, b_hh, P_c);
    k_rnn<<<32, 512, 0, stream>>>(len, Wb8, P_c, hfin);
    dim3 g3(16, 8);
    k_mlp<<<g3, 256, 0, stream>>>(hfin, l0_w, l0_b, a_buf);
    k_out<<<16, 256, 0, stream>>>(a_buf, l1_w, l1_b, out);
}

// Round 5
// 374.170 us; speedup vs baseline: 12.4967x; 1.0534x over previous
//
#include <hip/hip_runtime.h>
#include <hip/hip_bf16.h>
#include <cstdint>

// Problem constants
#define BB 512      // batch
#define TT 128      // time steps
#define VV 50000
#define DD 300      // embed dim
#define HH 512      // hidden
#define MLPD 1024
#define CC 3

typedef __bf16 bf16x8 __attribute__((ext_vector_type(8)));
typedef float  f32x4  __attribute__((ext_vector_type(4)));
typedef int    v8i    __attribute__((ext_vector_type(8)));

struct alignas(8)  bf4 { __bf16 x, y, z, w; };

// fast tanh: 1 - 2/(exp(2x)+1). Saturates correctly at +/-1.
__device__ __forceinline__ float ftanh(float x) {
    float e = __expf(2.0f * x);
    return 1.0f - 2.0f * __builtin_amdgcn_rcpf(e + 1.0f);
}

// e8m0 scale bytes: value = 2^(E-127). A: h stored x16 -> scale 2^-4 (E=123).
// B: W stored x8 -> scale 2^-3 (E=124).
#define SCALE_A 0x7B7B7B7B
#define SCALE_B 0x7C7C7C7C

// ---------------------------------------------------------------------------
// k_prep_hh8: W_hh (fp32 [c][k]) -> fp8 e4m3 (x8) in MFMA B-frag order for
// 16x16x128: frag F = ((w*4+ct)*4+kch)*64 + lane (32 B each);
// lane = n + 16q holds B[c = w*64+ct*16+n][k = kch*128 + q*32 + j], j=0..31.
// ---------------------------------------------------------------------------
__global__ __launch_bounds__(256) void k_prep_hh8(
    const float* __restrict__ W, unsigned char* __restrict__ out)
{
    const int T = blockIdx.x * 256 + threadIdx.x;    // 0..8191
    const int lane = T & 63;
    const int kch = (T >> 6) & 3;
    const int ct  = (T >> 8) & 3;
    const int w   = (T >> 10) & 7;
    const int n = lane & 15, q = lane >> 4;
    const int c  = w * 64 + ct * 16 + n;
    const int k0 = kch * 128 + q * 32;
    const float* src = W + c * HH + k0;
    unsigned int wd[8];
    #pragma unroll
    for (int i = 0; i < 8; ++i) {
        float4 v = *(const float4*)(src + i * 4);
        unsigned int t0 = __builtin_amdgcn_cvt_pk_fp8_f32(v.x * 8.f, v.y * 8.f, 0, false);
        t0 = __builtin_amdgcn_cvt_pk_fp8_f32(v.z * 8.f, v.w * 8.f, t0, true);
        wd[i] = t0;
    }
    *(uint4*)(out + (size_t)T * 32)      = make_uint4(wd[0], wd[1], wd[2], wd[3]);
    *(uint4*)(out + (size_t)T * 32 + 16) = make_uint4(wd[4], wd[5], wd[6], wd[7]);
}

// ---------------------------------------------------------------------------
// k_prep_ih: W_ih (fp32 [c][k], K=300 zero-padded to 320) -> bf16 B-frag order
// for k_proj (16x16x32): b128 #U: lane=U&63, kc=(U>>6)%10, g=(U>>6)/10,
// wp=g&3, nt=g>>2; c = nt*64+wp*16+(lane&15), k = kc*32+(lane>>4)*8.
// ---------------------------------------------------------------------------
__global__ __launch_bounds__(256) void k_prep_ih(
    const float* __restrict__ W, __bf16* __restrict__ out)
{
    const int U = blockIdx.x * 256 + threadIdx.x;    // 0..20479
    const int lane = U & 63;
    const int rest = U >> 6;
    const int kc = rest % 10;
    const int g  = rest / 10;
    const int wp = g & 3, nt = g >> 2;
    const int c = nt * 64 + wp * 16 + (lane & 15);
    const int k = kc * 32 + (lane >> 4) * 8;
    bf16x8 o;
    #pragma unroll
    for (int j = 0; j < 8; ++j) {
        const int kk = k + j;
        o[j] = (__bf16)((kk < DD) ? W[c * DD + kk] : 0.f);
    }
    *(bf16x8*)(out + (size_t)U * 8) = o;
}

// ---------------------------------------------------------------------------
// k_proj: P_c[t] = C-frag-ordered (E[x[i,T-1-t]] @ W_ih^T + b_ih + b_hh).
// Grid (128 t, 8 i-tiles) x 256 thr (4 waves). COALESCED gather: wave wv
// stages rows wv*16..wv*16+15; lanes read consecutive float4s of one
// embedding row (1 KB/instr). Inactive rows staged as zeros (their P output
// = bias, discarded by k_rnn's hold-select).
// P_c flat bf16 index: (((t*32 + wg)*8 + nt)*64 + lane)*16 + wp*4 + r
// ---------------------------------------------------------------------------
__global__ __launch_bounds__(256, 2) void k_proj(
    const int* __restrict__ x, const int* __restrict__ lengths,
    const float* __restrict__ E, const __bf16* __restrict__ Wih,
    const float* __restrict__ b_ih, const float* __restrict__ b_hh,
    __bf16* __restrict__ P_c)
{
    __shared__ __bf16 Afs[40 * 64 * 8];   // 40 KB, A-frag layout
    __shared__ float bias_s[HH];

    const int t   = blockIdx.x;
    const int i0  = blockIdx.y * 64;
    const int wg0 = blockIdx.y * 4;
    const int tid = threadIdx.x;
    const int wv = tid >> 6, lane = tid & 63;
    const int thr = TT - 1 - t;

    bias_s[tid]       = b_ih[tid]       + b_hh[tid];
    bias_s[tid + 256] = b_ih[tid + 256] + b_hh[tid + 256];

    // ---- coalesced gather: 16 rows per wave ----
    // pass A: lane reads float4 #lane (k0 = lane*4, 0..255)
    // pass B: lanes 0..10 read k0 = 256+lane*4 (256..296); lanes 11..15
    //         write zero pads (k0 = 300..316). Together k covers 0..319.
    {
        const int k0a = lane * 4;
        const int cha = wv * 10 + (k0a >> 5);
        const int ga  = (k0a >> 3) & 3;
        const int k0b = 256 + lane * 4;                 // 256..316 for lanes 0..15
        const int chb = wv * 10 + (k0b >> 5);
        const int gb  = (k0b >> 3) & 3;
        #pragma unroll 4
        for (int rl = 0; rl < 16; ++rl) {
            const int row = wv * 16 + rl;
            const int gr  = i0 + row;
            const bool act = thr < lengths[gr];          // broadcast load
            float4 v0 = make_float4(0.f, 0.f, 0.f, 0.f);
            float4 v1 = make_float4(0.f, 0.f, 0.f, 0.f);
            if (act) {
                const float* erow = E + (size_t)x[gr * TT + thr] * DD;
                v0 = *(const float4*)(erow + k0a);
                if (lane < 11) v1 = *(const float4*)(erow + k0b);
            }
            const int n15 = row & 15;
            bf4 p0 = {(__bf16)v0.x, (__bf16)v0.y, (__bf16)v0.z, (__bf16)v0.w};
            *(bf4*)(&Afs[((cha * 64) + n15 + 16 * ga) * 8 + (k0a & 7)]) = p0;
            if (lane < 16) {
                bf4 p1 = {(__bf16)v1.x, (__bf16)v1.y, (__bf16)v1.z, (__bf16)v1.w};
                *(bf4*)(&Afs[((chb * 64) + n15 + 16 * gb) * 8 + (k0b & 7)]) = p1;
            }
        }
    }
    __syncthreads();

    bf16x8 Af[4][10];
    #pragma unroll
    for (int ms = 0; ms < 4; ++ms)
        #pragma unroll
        for (int kc = 0; kc < 10; ++kc)
            Af[ms][kc] = *(const bf16x8*)(&Afs[((ms * 10 + kc) * 64 + lane) * 8]);

    const int wp = wv;
    for (int nt = 0; nt < 8; ++nt) {
        const __bf16* bbase = Wih + ((size_t)((nt * 4 + wp) * 10) * 64 + lane) * 8;
        bf16x8 Bf[10];
        #pragma unroll
        for (int kc = 0; kc < 10; ++kc)
            Bf[kc] = *(const bf16x8*)(bbase + (size_t)kc * 512);

        f32x4 acc[4] = {};
        #pragma unroll
        for (int kc = 0; kc < 10; ++kc) {
            acc[0] = __builtin_amdgcn_mfma_f32_16x16x32_bf16(Af[0][kc], Bf[kc], acc[0], 0, 0, 0);
            acc[1] = __builtin_amdgcn_mfma_f32_16x16x32_bf16(Af[1][kc], Bf[kc], acc[1], 0, 0, 0);
            acc[2] = __builtin_amdgcn_mfma_f32_16x16x32_bf16(Af[2][kc], Bf[kc], acc[2], 0, 0, 0);
            acc[3] = __builtin_amdgcn_mfma_f32_16x16x32_bf16(Af[3][kc], Bf[kc], acc[3], 0, 0, 0);
        }

        const float bias = bias_s[nt * 64 + wp * 16 + (lane & 15)];
        #pragma unroll
        for (int ms = 0; ms < 4; ++ms) {
            bf4 pk = {(__bf16)(acc[ms][0] + bias), (__bf16)(acc[ms][1] + bias),
                      (__bf16)(acc[ms][2] + bias), (__bf16)(acc[ms][3] + bias)};
            const size_t off = ((size_t)(((t * 32 + wg0 + ms) * 8 + nt) * 64 + lane)) * 16 + wp * 4;
            *(bf4*)(P_c + off) = pk;
        }
    }
}

// ---------------------------------------------------------------------------
// k_rnn: fp8-MX recurrence, DOUBLE-BUFFERED Hs -> ONE barrier/step.
// 32 WGs x 512 thr (8 waves, 2/SIMD). W_hh fp8 64-col wave slice in regs
// (128 VGPRs). h fp8 (x16) in LDS A-frag layout for 16x16x128, 2 x 8 KB
// ping-pong. Carry-semantics via per-lane register hold[4][4] (a lane owns
// the same 16 (m,c) h-elements every step) -> unconditional LDS writes,
// straight-line epilogue. Per wave per step: 8 ds_read_b128 + 16 MFMA +
// 16 b8 writes + 1 barrier.
// ---------------------------------------------------------------------------
__global__ __launch_bounds__(512, 2) void k_rnn(
    const int* __restrict__ lengths, const unsigned char* __restrict__ Wb8,
    const __bf16* __restrict__ P_c, __bf16* __restrict__ h_final)
{
    __shared__ unsigned char Hs8[2][8192];

    const int tid = threadIdx.x;
    const int wg  = blockIdx.x;
    const int r0  = wg * 16;
    const int w    = tid >> 6;
    const int lane = tid & 63;
    const int n = lane & 15, q = lane >> 4;

    // zero buffer 0 (read at t=0); buffer 1 fully written at t=0
    for (int i = tid * 16; i < 8192; i += 512 * 16)
        *(uint4*)(&Hs8[0][i]) = make_uint4(0u, 0u, 0u, 0u);

    int lens_v[4];
    #pragma unroll
    for (int r = 0; r < 4; ++r) lens_v[r] = lengths[r0 + q * 4 + r];

    // whole 64-col W slice -> registers (128 VGPRs)
    v8i Bv[4][4];
    #pragma unroll
    for (int ct = 0; ct < 4; ++ct)
        #pragma unroll
        for (int kch = 0; kch < 4; ++kch)
            Bv[ct][kch] = *(const v8i*)(Wb8 + ((size_t)(((w * 4 + ct) * 4 + kch) * 64 + lane)) * 32);

    // per-lane epilogue write addresses (t-invariant): col c = w*64+ct*16+n
    int wbase[4];
    #pragma unroll
    for (int ct = 0; ct < 4; ++ct) {
        const int kch_w = (4 * w + ct) >> 3;
        const int qp    = (2 * w + (ct >> 1)) & 3;
        const int jb    = 16 * (ct & 1) + n;
        wbase[ct] = (kch_w * 64 + 16 * qp + q * 4) * 32 + jb;
    }

    float hold[4][4] = {};    // this lane's 16 h values (carry registers)

    __syncthreads();

    const __bf16* pcb = P_c + ((size_t)(wg * 8 + w) * 64 + lane) * 16;

    for (int t = 0; t < TT; ++t) {
        bf16x8 pva = *(const bf16x8*)(pcb + (size_t)t * 262144);
        bf16x8 pvb = *(const bf16x8*)(pcb + (size_t)t * 262144 + 8);

        const unsigned char* rbuf = Hs8[t & 1];
        unsigned char*       wbuf = Hs8[(t + 1) & 1];

        f32x4 acc[4] = {};
        #pragma unroll
        for (int kch = 0; kch < 4; ++kch) {
            v8i a = *(const v8i*)(&rbuf[(kch * 64 + lane) * 32]);
            acc[0] = __builtin_amdgcn_mfma_scale_f32_16x16x128_f8f6f4(
                         a, Bv[0][kch], acc[0], 0, 0, 0, SCALE_A, 0, SCALE_B);
            acc[1] = __builtin_amdgcn_mfma_scale_f32_16x16x128_f8f6f4(
                         a, Bv[1][kch], acc[1], 0, 0, 0, SCALE_A, 0, SCALE_B);
            acc[2] = __builtin_amdgcn_mfma_scale_f32_16x16x128_f8f6f4(
                         a, Bv[2][kch], acc[2], 0, 0, 0, SCALE_A, 0, SCALE_B);
            acc[3] = __builtin_amdgcn_mfma_scale_f32_16x16x128_f8f6f4(
                         a, Bv[3][kch], acc[3], 0, 0, 0, SCALE_A, 0, SCALE_B);
        }

        const int thr = TT - 1 - t;
        #pragma unroll
        for (int ct = 0; ct < 4; ++ct) {
            #pragma unroll
            for (int r = 0; r < 4; ++r) {
                const int idx = ct * 4 + r;
                const float pvf = (float)((idx < 8) ? pva[idx] : pvb[idx - 8]);
                const float th = ftanh(acc[ct][r] + pvf);
                const float hv = (thr < lens_v[r]) ? th : hold[ct][r];
                hold[ct][r] = hv;
                const unsigned int pw =
                    __builtin_amdgcn_cvt_pk_fp8_f32(hv * 16.f, hv * 16.f, 0u, false);
                wbuf[wbase[ct] + r * 32] = (unsigned char)(pw & 0xffu);
            }
        }
        __syncthreads();   // wbuf complete before next step reads it
    }

    // drain: final h is in Hs8[0] (written at t=127). fp8 frag -> bf16 rows.
    {
        const int half   = tid & 1;
        const int lane_t = (tid >> 1) & 63;
        const int kch    = tid >> 7;
        const int m  = lane_t & 15, qq = lane_t >> 4;
        const int cb = kch * 128 + qq * 32 + half * 16;
        uint4 wv = *(const uint4*)(&Hs8[0][(kch * 64 + lane_t) * 32 + half * 16]);
        unsigned int ws4[4] = {wv.x, wv.y, wv.z, wv.w};
        bf16x8 o0, o1;
        #pragma unroll
        for (int wd = 0; wd < 4; ++wd) {
            float f0 = __builtin_amdgcn_cvt_f32_fp8(ws4[wd], 0) * 0.0625f;
            float f1 = __builtin_amdgcn_cvt_f32_fp8(ws4[wd], 1) * 0.0625f;
            float f2 = __builtin_amdgcn_cvt_f32_fp8(ws4[wd], 2) * 0.0625f;
            float f3 = __builtin_amdgcn_cvt_f32_fp8(ws4[wd], 3) * 0.0625f;
            if (wd < 2) {
                o0[wd * 4 + 0] = (__bf16)f0; o0[wd * 4 + 1] = (__bf16)f1;
                o0[wd * 4 + 2] = (__bf16)f2; o0[wd * 4 + 3] = (__bf16)f3;
            } else {
                o1[(wd - 2) * 4 + 0] = (__bf16)f0; o1[(wd - 2) * 4 + 1] = (__bf16)f1;
                o1[(wd - 2) * 4 + 2] = (__bf16)f2; o1[(wd - 2) * 4 + 3] = (__bf16)f3;
            }
        }
        *(bf16x8*)(h_final + (size_t)(r0 + m) * HH + cb)     = o0;
        *(bf16x8*)(h_final + (size_t)(r0 + m) * HH + cb + 8) = o1;
    }
}

// ---------------------------------------------------------------------------
// k_mlp: a = relu(h @ l0_w^T + l0_b), fp32 out. 64x64 tiles, K=512.
// ---------------------------------------------------------------------------
#define LKH 520

__global__ __launch_bounds__(256) void k_mlp(
    const __bf16* __restrict__ hfin, const float* __restrict__ l0_w,
    const float* __restrict__ l0_b, float* __restrict__ a_buf)
{
    __shared__ __bf16 As[64 * LKH];
    __shared__ __bf16 Bs[64 * LKH];
    const int i0  = blockIdx.y * 64;
    const int n0  = blockIdx.x * 64;
    const int tid = threadIdx.x;

    {
        const int row = tid >> 2, kq = tid & 3;
        const __bf16* asrc = hfin + (i0 + row) * HH + kq * 128;
        __bf16* adst = &As[row * LKH + kq * 128];
        #pragma unroll
        for (int j = 0; j < 128; j += 8)
            *(uint4*)(adst + j) = *(const uint4*)(asrc + j);
        const float* bsrc = l0_w + (n0 + row) * HH + kq * 128;
        __bf16* bdst = &Bs[row * LKH + kq * 128];
        #pragma unroll
        for (int j = 0; j < 128; j += 4) {
            float4 v = *(const float4*)(bsrc + j);
            bf4 pk = {(__bf16)v.x, (__bf16)v.y, (__bf16)v.z, (__bf16)v.w};
            *(bf4*)(bdst + j) = pk;
        }
    }
    __syncthreads();

    const int wave = tid >> 6, lane = tid & 63;
    const int wm = (wave & 1) * 32, wn = (wave >> 1) * 32;
    const int lr = lane & 15, kk = (lane >> 4) * 8;
    f32x4 acc[2][2] = {};
    #pragma unroll
    for (int kc = 0; kc < 16; ++kc) {
        const int kb = kc * 32 + kk;
        bf16x8 a0 = *(const bf16x8*)(&As[(wm      + lr) * LKH + kb]);
        bf16x8 a1 = *(const bf16x8*)(&As[(wm + 16 + lr) * LKH + kb]);
        bf16x8 b0 = *(const bf16x8*)(&Bs[(wn      + lr) * LKH + kb]);
        bf16x8 b1 = *(const bf16x8*)(&Bs[(wn + 16 + lr) * LKH + kb]);
        acc[0][0] = __builtin_amdgcn_mfma_f32_16x16x32_bf16(a0, b0, acc[0][0], 0, 0, 0);
        acc[0][1] = __builtin_amdgcn_mfma_f32_16x16x32_bf16(a0, b1, acc[0][1], 0, 0, 0);
        acc[1][0] = __builtin_amdgcn_mfma_f32_16x16x32_bf16(a1, b0, acc[1][0], 0, 0, 0);
        acc[1][1] = __builtin_amdgcn_mfma_f32_16x16x32_bf16(a1, b1, acc[1][1], 0, 0, 0);
    }

    const int mrow = (lane >> 4) * 4, ncol = lane & 15;
    #pragma unroll
    for (int ni = 0; ni < 2; ++ni) {
        const int nl = wn + ni * 16 + ncol;
        const float bias = l0_b[n0 + nl];
        #pragma unroll
        for (int mi = 0; mi < 2; ++mi) {
            #pragma unroll
            for (int r = 0; r < 4; ++r) {
                const int ml = wm + mi * 16 + mrow + r;
                a_buf[(i0 + ml) * MLPD + (n0 + nl)] = fmaxf(acc[mi][ni][r] + bias, 0.f);
            }
        }
    }
}

// ---------------------------------------------------------------------------
// k_out: logits = relu(a @ l1_w^T + l1_b); out = log_softmax(logits).
// ---------------------------------------------------------------------------
__global__ __launch_bounds__(256) void k_out(
    const float* __restrict__ a_buf, const float* __restrict__ l1_w,
    const float* __restrict__ l1_b, float* __restrict__ out)
{
    __shared__ float red[32][8][3];
    const int tid = threadIdx.x;
    const int r = tid >> 3, p = tid & 7;
    const int row = blockIdx.x * 32 + r;
    const float* arow = a_buf + row * MLPD + p * 128;
    float pl0 = 0.f, pl1 = 0.f, pl2 = 0.f;
    #pragma unroll 8
    for (int j = 0; j < 128; j += 4) {
        float4 av = *(const float4*)(arow + j);
        float4 w0 = *(const float4*)(l1_w + 0 * MLPD + p * 128 + j);
        float4 w1 = *(const float4*)(l1_w + 1 * MLPD + p * 128 + j);
        float4 w2 = *(const float4*)(l1_w + 2 * MLPD + p * 128 + j);
        pl0 += av.x * w0.x + av.y * w0.y + av.z * w0.z + av.w * w0.w;
        pl1 += av.x * w1.x + av.y * w1.y + av.z * w1.z + av.w * w1.w;
        pl2 += av.x * w2.x + av.y * w2.y + av.z * w2.z + av.w * w2.w;
    }
    red[r][p][0] = pl0; red[r][p][1] = pl1; red[r][p][2] = pl2;
    __syncthreads();
    if (p == 0) {
        float l[3];
        #pragma unroll
        for (int c = 0; c < 3; ++c) {
            float s = 0.f;
            #pragma unroll
            for (int qq = 0; qq < 8; ++qq) s += red[r][qq][c];
            s += l1_b[c];
            l[c] = fmaxf(s, 0.f);
        }
        float m = fmaxf(l[0], fmaxf(l[1], l[2]));
        float sum = expf(l[0] - m) + expf(l[1] - m) + expf(l[2] - m);
        float ls = m + logf(sum);
        out[row * CC + 0] = l[0] - ls;
        out[row * CC + 1] = l[1] - ls;
        out[row * CC + 2] = l[2] - ls;
    }
}

// ---------------------------------------------------------------------------
extern "C" void kernel_launch(void* const* d_in, const int* in_sizes, int n_in,
                              void* d_out, int out_size, void* d_ws, size_t ws_size,
                              hipStream_t stream) {
    const int*   x    = (const int*)  d_in[0];
    const int*   len  = (const int*)  d_in[1];
    const float* E    = (const float*)d_in[2];
    const float* W_ih = (const float*)d_in[3];
    const float* b_ih = (const float*)d_in[4];
    const float* W_hh = (const float*)d_in[5];
    const float* b_hh = (const float*)d_in[6];
    const float* l0_w = (const float*)d_in[7];
    const float* l0_b = (const float*)d_in[8];
    const float* l1_w = (const float*)d_in[9];
    const float* l1_b = (const float*)d_in[10];
    float* out = (float*)d_out;

    char* ws = (char*)d_ws;
    // layout: Wb8 fp8 @0 (256KB); Wih_frag @512KB (320KB); h_final @1MB
    // (512KB); P_c @2MB (64MB: 128*512*512 bf16); a_buf @66MB (2MB). ~68MB.
    unsigned char* Wb8 = (unsigned char*)ws;
    __bf16* Wih   = (__bf16*)(ws + 524288);
    __bf16* hfin  = (__bf16*)(ws + 1048576);
    __bf16* P_c   = (__bf16*)(ws + 2097152);
    float*  a_buf = (float*) (ws + 2097152 + 67108864ull);

    k_prep_hh8<<<32, 256, 0, stream>>>(W_hh, Wb8);
    k_prep_ih<<<80, 256, 0, stream>>>(W_ih, Wih);
    dim3 g1(128, 8);
    k_proj<<<g1, 256, 0, stream>>>(x, len, E, Wih, b_ih, b_hh, P_c);
    k_rnn<<<32, 512, 0, stream>>>(len, Wb8, P_c, hfin);
    dim3 g3(16, 8);
    k_mlp<<<g3, 256, 0, stream>>>(hfin, l0_w, l0_b, a_buf);
    k_out<<<16, 256, 0, stream>>>(a_buf, l1_w, l1_b, out);
}